// Round 13
// baseline (11586.263 us; speedup 1.0000x reference)
//
#include <hip/hip_runtime.h>
#include <hip/hip_bf16.h>

#define B_    256
#define S_    512
#define H_    256
#define TLEN_ 32
#define DI_   5
#define ENCSTRIDE 131072   // S_*H_
#define CHUNK 32
#define NCHUNK 16          // S_/CHUNK
#define NB 2               // batches per encoder block (256 blocks -> all CUs)

__device__ __forceinline__ float bf2f(unsigned short v) {
    return __uint_as_float(((unsigned)v) << 16);
}
__device__ __forceinline__ unsigned short f2bf(float f) {
    __hip_bfloat16 h = __float2bfloat16(f);
    return *reinterpret_cast<unsigned short*>(&h);
}

// ---------------------------------------------------------------------------
// init: set decoder inp0 = ones
// ---------------------------------------------------------------------------
__global__ __launch_bounds__(256) void init_kernel(float* PRD) {
    int i = blockIdx.x * 256 + threadIdx.x;      // grid 8 -> 2048
    if (i < B_ * DI_) PRD[i] = 1.0f;
}

// ---------------------------------------------------------------------------
// pack a [1024][256] row-major weight into [k4][n] float4 layout (fp32):
// out[k4*1024 + n] = {w[n][4k4], w[n][4k4+1], w[n][4k4+2], w[n][4k4+3]}
// ---------------------------------------------------------------------------
__global__ __launch_bounds__(256) void pack_kernel(const float* __restrict__ m,
                                                   float4* __restrict__ out) {
    int idx = blockIdx.x * 256 + threadIdx.x;    // grid 256 -> 65536
    int k4 = idx >> 10, n = idx & 1023;
    out[idx] = ((const float4*)m)[n * 64 + k4];
}

// ---------------------------------------------------------------------------
// same pack, bf16 payload (ushort4 = 4 weights / 8B): halves weight streams.
// ---------------------------------------------------------------------------
__global__ __launch_bounds__(256) void packbf_kernel(const float* __restrict__ m,
                                                     ushort4* __restrict__ out) {
    int idx = blockIdx.x * 256 + threadIdx.x;    // grid 256 -> 65536
    int k4 = idx >> 10, n = idx & 1023;
    float4 v = ((const float4*)m)[n * 64 + k4];
    out[idx] = make_ushort4(f2bf(v.x), f2bf(v.y), f2bf(v.z), f2bf(v.w));
}

// ---------------------------------------------------------------------------
// Weff[n][m] = sum_k wih_d1[n][k]*wdi[k][m]; beff[n] = b_d1[n] + wih_d1[n]·bdi
// ---------------------------------------------------------------------------
__global__ __launch_bounds__(256) void weff_kernel(const float* __restrict__ wih_d1,
                                                   const float* __restrict__ wdi,
                                                   const float* __restrict__ bdi,
                                                   const float* __restrict__ b_d1,
                                                   float* __restrict__ weff,
                                                   float* __restrict__ beff) {
    int n = blockIdx.x * 256 + threadIdx.x;      // grid 4 -> 1024
    float acc[DI_] = {0.f, 0.f, 0.f, 0.f, 0.f};
    float accb = 0.f;
    for (int k = 0; k < H_; k++) {
        float w = wih_d1[n * H_ + k];
        accb += w * bdi[k];
#pragma unroll
        for (int m = 0; m < DI_; m++) acc[m] += w * wdi[k * DI_ + m];
    }
#pragma unroll
    for (int m = 0; m < DI_; m++) weff[n * DI_ + m] = acc[m];
    beff[n] = b_d1[n] + accb;
}

// ---------------------------------------------------------------------------
// dot-chunk helper: a0..a3 += xv · w{0..3}
// ---------------------------------------------------------------------------
__device__ __forceinline__ void dot4(const float4 xv, const float4 w0, const float4 w1,
                                     const float4 w2, const float4 w3,
                                     float& a0, float& a1, float& a2, float& a3) {
    a0 += xv.x * w0.x + xv.y * w0.y + xv.z * w0.z + xv.w * w0.w;
    a1 += xv.x * w1.x + xv.y * w1.y + xv.z * w1.z + xv.w * w1.w;
    a2 += xv.x * w2.x + xv.y * w2.y + xv.z * w2.z + xv.w * w2.w;
    a3 += xv.x * w3.x + xv.y * w3.y + xv.z * w3.z + xv.w * w3.w;
}

__device__ __forceinline__ float4 bf4f(ushort4 u) {
    return make_float4(bf2f(u.x), bf2f(u.y), bf2f(u.z), bf2f(u.w));
}

__device__ __forceinline__ void lstm_epilogue(float a0, float a1, float a2, float a3,
                                              float cold, float& cn, float& hn) {
    float ii = 1.f / (1.f + expf(-a0));
    float ff = 1.f / (1.f + expf(-a1));
    float gg = tanhf(a2);
    float oo = 1.f / (1.f + expf(-a3));
    cn = ff * cold + ii * gg;
    hn = oo * tanhf(cn);
}

// ---------------------------------------------------------------------------
// xproj (r10-proven v1): X2[u][b][n] = sum_k wih_e2[n][k] * e1[u][b][k].
// Weight-stationary; e1 broadcast from LDS. (v2's 32-row variant regressed:
// VGPR 116 + 99KB LDS halved occupancy -- do not reintroduce.)
// ---------------------------------------------------------------------------
__global__ __launch_bounds__(512) void xproj_kernel(
    const float* __restrict__ h1,      // [CHUNK][B_][H_]
    const float4* __restrict__ wp,     // packed [64][1024] (PKX2)
    float* __restrict__ X2)            // [CHUNK*B_][1024]
{
    __shared__ float es[16][260];      // 16 staged e1 rows
    __shared__ float red[8][16][64];   // [kh][row][nl]
    int tid = threadIdx.x;
    int nt = blockIdx.x & 15, rg = blockIdx.x >> 4;
    int nl = tid & 63, kh = tid >> 6;  // kh in [0,8)
    int n = nt * 64 + nl;

    float4 w[8];
#pragma unroll
    for (int q = 0; q < 8; q++) w[q] = wp[(((kh << 3) + q) << 10) + n];

    for (int rnd = 0; rnd < 32; rnd++) {
        int r0 = rg * 512 + rnd * 16;
        for (int i = tid; i < 1024; i += 512) {
            int rr = i >> 6, c4 = i & 63;
            ((float4*)&es[rr][0])[c4] = ((const float4*)(h1 + (long)(r0 + rr) * H_))[c4];
        }
        __syncthreads();
        float acc[16];
#pragma unroll
        for (int rr = 0; rr < 16; rr++) acc[rr] = 0.f;
#pragma unroll
        for (int q = 0; q < 8; q++) {
            float4 wq = w[q];
#pragma unroll
            for (int rr = 0; rr < 16; rr++) {
                float4 e = ((const float4*)&es[rr][0])[(kh << 3) + q];
                acc[rr] += e.x * wq.x + e.y * wq.y + e.z * wq.z + e.w * wq.w;
            }
        }
#pragma unroll
        for (int rr = 0; rr < 16; rr++) red[kh][rr][nl] = acc[rr];
        __syncthreads();
        for (int rr = kh; rr < 16; rr += 8) {
            float s = 0.f;
#pragma unroll
            for (int kk = 0; kk < 8; kk++) s += red[kk][rr][nl];
            X2[(long)(r0 + rr) * 1024 + n] = s;
        }
        __syncthreads();               // X2/red reads done before next stage
    }
}

// ---------------------------------------------------------------------------
// Chunked encoder NB=2 with BF16 recurrent weights (r12-proven):
// per-CU whh stream 0.5MB/step; r5 inner loops.
// ---------------------------------------------------------------------------
__global__ __launch_bounds__(1024, 4) void enc_chunk_kernel(
    int ci,
    const float* __restrict__ srcs,
    const float* __restrict__ wih_e1,      // [1024][5] raw
    const ushort4* __restrict__ whh_e1p,   // packed bf16 [64][1024]
    const ushort4* __restrict__ whh_e2p,   // packed bf16 [64][1024]
    const float* __restrict__ b_e1,
    const float* __restrict__ b_e2,
    const float* __restrict__ X2,          // [CHUNK*B_][1024] wih_e2 part
    float* __restrict__ H1G,               // [CHUNK][B_][H_] (single buffer)
    float* __restrict__ C1C,               // [B_][H_] layer-1 c carry
    float* __restrict__ H2C,               // [B_][H_] layer-2 h carry (final = h_enc)
    float* __restrict__ C2C,               // [B_][H_] layer-2 c carry (final = c_enc)
    __hip_bfloat16* __restrict__ encbf)    // [b][s][h]
{
    __shared__ float4 red[4][NB][256];     // [kh][bb][j] -> 4 gate partials, 32KB
    __shared__ float hb[NB][260];          // own-layer h (current step)
    __shared__ float sS[NB][160];          // L1 srcs chunk

    int tid = threadIdx.x;
    int kh = tid >> 8;                     // K-slice (accum); bb in reduce (kh<NB)
    int j  = tid & 255;
    int k40 = kh << 4;                     // 16 k4 iterations per slice

    if (blockIdx.x < 128) {
        // ================= layer 1, chunk ci =================
        if (ci >= NCHUNK) return;
        int b0 = blockIdx.x * NB;
        int ts = ci * CHUNK;

        for (int idx = tid; idx < NB * CHUNK * DI_; idx += 1024) {
            int r = idx / (CHUNK * DI_), off = idx - r * (CHUNK * DI_);
            sS[r][off] = srcs[((long)(b0 + r) * S_ + ts) * DI_ + off];
        }
        float creg = 0.f;
        if (kh < NB) {
            hb[kh][j] = (ci == 0) ? 0.f : H1G[(CHUNK - 1) * 65536 + (b0 + kh) * H_ + j];
            creg = (ci == 0) ? 0.f : C1C[(b0 + kh) * H_ + j];
        }
        float bias0 = b_e1[j], bias1 = b_e1[256 + j], bias2 = b_e1[512 + j], bias3 = b_e1[768 + j];
        float wx[4][DI_];
#pragma unroll
        for (int k = 0; k < DI_; k++) {
            wx[0][k] = wih_e1[j * DI_ + k];
            wx[1][k] = wih_e1[(256 + j) * DI_ + k];
            wx[2][k] = wih_e1[(512 + j) * DI_ + k];
            wx[3][k] = wih_e1[(768 + j) * DI_ + k];
        }

        for (int tt = 0; tt < CHUNK; tt++) {
            __syncthreads();               // hb ready; prev red reads done
            float A[NB][4];
#pragma unroll
            for (int bb = 0; bb < NB; bb++) {
                A[bb][0] = 0.f; A[bb][1] = 0.f; A[bb][2] = 0.f; A[bb][3] = 0.f;
            }
            if (kh == 0) {                 // input projection K=5 (wave-uniform branch)
#pragma unroll
                for (int bb = 0; bb < NB; bb++)
#pragma unroll
                    for (int k = 0; k < DI_; k++) {
                        float xv = sS[bb][tt * DI_ + k];
                        A[bb][0] += xv * wx[0][k];
                        A[bb][1] += xv * wx[1][k];
                        A[bb][2] += xv * wx[2][k];
                        A[bb][3] += xv * wx[3][k];
                    }
            }
#pragma unroll 4
            for (int k4 = k40; k4 < k40 + 16; k4++) {
                float4 w0 = bf4f(whh_e1p[(k4 << 10) + j]);
                float4 w1 = bf4f(whh_e1p[(k4 << 10) + 256 + j]);
                float4 w2 = bf4f(whh_e1p[(k4 << 10) + 512 + j]);
                float4 w3 = bf4f(whh_e1p[(k4 << 10) + 768 + j]);
#pragma unroll
                for (int bb = 0; bb < NB; bb++) {
                    float4 h4 = ((const float4*)&hb[bb][0])[k4];
                    dot4(h4, w0, w1, w2, w3, A[bb][0], A[bb][1], A[bb][2], A[bb][3]);
                }
            }
#pragma unroll
            for (int bb = 0; bb < NB; bb++)
                red[kh][bb][j] = make_float4(A[bb][0], A[bb][1], A[bb][2], A[bb][3]);
            __syncthreads();               // red complete; hb reads done
            if (kh < NB) {
                float a0 = bias0, a1 = bias1, a2 = bias2, a3 = bias3;
#pragma unroll
                for (int kk = 0; kk < 4; kk++) {
                    float4 v = red[kk][kh][j];
                    a0 += v.x; a1 += v.y; a2 += v.z; a3 += v.w;
                }
                float cn, hn;
                lstm_epilogue(a0, a1, a2, a3, creg, cn, hn);
                creg = cn;
                hb[kh][j] = hn;
                H1G[tt * 65536 + (b0 + kh) * H_ + j] = hn;
            }
        }
        if (kh < NB) C1C[(b0 + kh) * H_ + j] = creg;
    } else {
        // ================= layer 2, chunk ci-1 =================
        if (ci < 1) return;
        int b0 = (blockIdx.x - 128) * NB;
        int us = (ci - 1) * CHUNK;

        float creg = 0.f, hlast = 0.f;
        if (kh < NB) {
            hb[kh][j] = (ci == 1) ? 0.f : H2C[(b0 + kh) * H_ + j];
            creg = (ci == 1) ? 0.f : C2C[(b0 + kh) * H_ + j];
        }
        float bias0 = b_e2[j], bias1 = b_e2[256 + j], bias2 = b_e2[512 + j], bias3 = b_e2[768 + j];

        for (int tt = 0; tt < CHUNK; tt++) {
            __syncthreads();               // hb ready; prev red reads done
            float x0 = 0.f, x1 = 0.f, x2 = 0.f, x3 = 0.f;
            if (kh < NB) {                 // prefetch own X2 row (hidden under k4 loop)
                const float* xrow = X2 + ((long)tt * B_ + b0 + kh) * 1024;
                x0 = xrow[j]; x1 = xrow[256 + j]; x2 = xrow[512 + j]; x3 = xrow[768 + j];
            }
            float A[NB][4];
#pragma unroll
            for (int bb = 0; bb < NB; bb++) {
                A[bb][0] = 0.f; A[bb][1] = 0.f; A[bb][2] = 0.f; A[bb][3] = 0.f;
            }
#pragma unroll 4
            for (int k4 = k40; k4 < k40 + 16; k4++) {
                float4 w0 = bf4f(whh_e2p[(k4 << 10) + j]);
                float4 w1 = bf4f(whh_e2p[(k4 << 10) + 256 + j]);
                float4 w2 = bf4f(whh_e2p[(k4 << 10) + 512 + j]);
                float4 w3 = bf4f(whh_e2p[(k4 << 10) + 768 + j]);
#pragma unroll
                for (int bb = 0; bb < NB; bb++) {
                    float4 h4 = ((const float4*)&hb[bb][0])[k4];
                    dot4(h4, w0, w1, w2, w3, A[bb][0], A[bb][1], A[bb][2], A[bb][3]);
                }
            }
#pragma unroll
            for (int bb = 0; bb < NB; bb++)
                red[kh][bb][j] = make_float4(A[bb][0], A[bb][1], A[bb][2], A[bb][3]);
            __syncthreads();               // red complete; hb reads done
            if (kh < NB) {
                float a0 = bias0 + x0, a1 = bias1 + x1, a2 = bias2 + x2, a3 = bias3 + x3;
#pragma unroll
                for (int kk = 0; kk < 4; kk++) {
                    float4 v = red[kk][kh][j];
                    a0 += v.x; a1 += v.y; a2 += v.z; a3 += v.w;
                }
                float cn, hn;
                lstm_epilogue(a0, a1, a2, a3, creg, cn, hn);
                creg = cn;
                hlast = hn;
                hb[kh][j] = hn;
                encbf[(long)(b0 + kh) * ENCSTRIDE + (us + tt) * H_ + j] = __float2bfloat16(hn);
            }
        }
        if (kh < NB) {
            H2C[(b0 + kh) * H_ + j] = hlast;
            C2C[(b0 + kh) * H_ + j] = creg;
        }
    }
}

// ---------------------------------------------------------------------------
// Decoder step: cell1 + cell2 + energies in ONE launch. BF16 cell weights
// (halves the 2MB/CU/step stream; same transform proven on encoder r12).
// 128 blocks x 1024 threads; block owns 2 batches, all 1024 gates (j = tid).
// Energies: float2 loads, 4 bf16/lane (64 x 4 = 256 = H_).
// ---------------------------------------------------------------------------
__global__ __launch_bounds__(1024) void dec_step_kernel(
    const float* __restrict__ PRD,
    const float* __restrict__ WEF,       // [1024][5]
    const float* __restrict__ BEF,       // [1024]
    const ushort4* __restrict__ whhd1p,  // packed bf16 [64][1024]
    const ushort4* __restrict__ wihd2p,  // packed bf16 [64][1024]
    const float* __restrict__ b_d2,
    float* __restrict__ H2C,             // in: h2prev, out: h2new (own rows only)
    float* __restrict__ C2C,             // in: c2prev, out: c2new (own rows only)
    const __hip_bfloat16* __restrict__ enc,
    float* __restrict__ E)               // [S_][B_]
{
    __shared__ float h2s[2][260];        // h2prev
    __shared__ float h1s[2][260];
    __shared__ float h2n[2][260];        // h2 new
    __shared__ float g[2][1024];         // gate accum staging
    __shared__ float prd[2][8];
    int tid = threadIdx.x;
    int j = tid;
    int b0 = blockIdx.x * 2;

    if (tid < 512) h2s[tid >> 8][tid & 255] = H2C[(b0 + (tid >> 8)) * H_ + (tid & 255)];
    if (tid < 2 * DI_) prd[tid / DI_][tid % DI_] = PRD[(b0 + tid / DI_) * DI_ + tid % DI_];
    __syncthreads();

    // ---- phase A: cell1 gates ----
    {
        float wef[DI_];
#pragma unroll
        for (int m = 0; m < DI_; m++) wef[m] = WEF[j * DI_ + m];
        float be = BEF[j];
        float a[2];
#pragma unroll
        for (int bb = 0; bb < 2; bb++) {
            a[bb] = be;
#pragma unroll
            for (int m = 0; m < DI_; m++) a[bb] += wef[m] * prd[bb][m];
        }
#pragma unroll 4
        for (int k4 = 0; k4 < 64; k4++) {
            float4 w = bf4f(whhd1p[(k4 << 10) + j]);
#pragma unroll
            for (int bb = 0; bb < 2; bb++) {
                float4 h4 = ((const float4*)&h2s[bb][0])[k4];
                a[bb] += h4.x * w.x + h4.y * w.y + h4.z * w.z + h4.w * w.w;
            }
        }
        g[0][j] = a[0]; g[1][j] = a[1];
    }
    __syncthreads();
    if (tid < 512) {
        int bb = tid >> 8, n = tid & 255;
        float cn, hn;
        lstm_epilogue(g[bb][n], g[bb][256 + n], g[bb][512 + n], g[bb][768 + n],
                      C2C[(b0 + bb) * H_ + n], cn, hn);
        h1s[bb][n] = hn;                 // c1 is not carried
    }
    __syncthreads();

    // ---- phase B: cell2 gates (h=c=0, no whh) ----
    {
        float b2 = b_d2[j];
        float a[2] = {b2, b2};
#pragma unroll 4
        for (int k4 = 0; k4 < 64; k4++) {
            float4 w = bf4f(wihd2p[(k4 << 10) + j]);
#pragma unroll
            for (int bb = 0; bb < 2; bb++) {
                float4 h4 = ((const float4*)&h1s[bb][0])[k4];
                a[bb] += h4.x * w.x + h4.y * w.y + h4.z * w.z + h4.w * w.w;
            }
        }
        g[0][j] = a[0]; g[1][j] = a[1];
    }
    __syncthreads();
    if (tid < 512) {
        int bb = tid >> 8, n = tid & 255;
        float cn, hn;
        lstm_epilogue(g[bb][n], g[bb][256 + n], g[bb][512 + n], g[bb][768 + n],
                      0.f, cn, hn);
        C2C[(b0 + bb) * H_ + n] = cn;
        H2C[(b0 + bb) * H_ + n] = hn;
        h2n[bb][n] = hn;
    }
    __syncthreads();

    // ---- phase C: energies (4 bf16 per lane: 64 x 4 = 256 = H_) ----
    {
        int wv = tid >> 6, lane = tid & 63;
        int bb = wv >> 3, ws = wv & 7;
        const __hip_bfloat16* ep = enc + (long)(b0 + bb) * ENCSTRIDE;
        float hreg[4];
#pragma unroll
        for (int q = 0; q < 4; q++) hreg[q] = h2n[bb][(lane << 2) + q];
        for (int si = 0; si < 64; si++) {
            int s = ws + (si << 3);
            union { float2 f2; unsigned short u[4]; } uu;
            uu.f2 = *(const float2*)(ep + s * H_ + (lane << 2));
            float p = hreg[0] * bf2f(uu.u[0]) + hreg[1] * bf2f(uu.u[1]) +
                      hreg[2] * bf2f(uu.u[2]) + hreg[3] * bf2f(uu.u[3]);
#pragma unroll
            for (int off = 32; off > 0; off >>= 1) p += __shfl_down(p, off);
            if (lane == 0) E[s * B_ + b0 + bb] = p;
        }
    }
}

// ---------------------------------------------------------------------------
// ctx_out with in-block softmax, THREAD-OWNS-ROW stats (r11-correctness-
// proven; r9's failure was wave-serial reduce-chains). Each of 256 threads
// scans its 2 E-rows with 64 independent float4 loads. E is L2-resident.
// max is order-independent; sum order differs at fp32 noise only.
// ---------------------------------------------------------------------------
__global__ __launch_bounds__(256) void ctx_out_kernel(
    const float* __restrict__ E,
    const __hip_bfloat16* __restrict__ enc,
    const float* __restrict__ h2,
    const float* __restrict__ ww, const float* __restrict__ bw,
    const float* __restrict__ wop, const float* __restrict__ bop,
    float* __restrict__ out_ctx,   // OUT1 + t*H_ pre-offset
    float* __restrict__ out0,      // OUT0 + t*DI_ pre-offset
    float* __restrict__ pred)
{
    __shared__ float ms[512], ssum[512];
    __shared__ float lw[512];
    __shared__ float hc[512];      // [h2 | ctx]
    int b = blockIdx.x, tid = threadIdx.x;

    hc[tid] = h2[b * H_ + tid];
    // softmax stats: thread owns rows {tid, tid+256}; independent float4 scans
#pragma unroll
    for (int r = 0; r < 2; r++) {
        int s = tid + (r << 8);
        const float4* er = (const float4*)(E + s * B_);
        float mx = -3.4e38f;
        for (int q = 0; q < 64; q++) {
            float4 e = er[q];
            mx = fmaxf(mx, fmaxf(fmaxf(e.x, e.y), fmaxf(e.z, e.w)));
        }
        float sm = 0.f;
        for (int q = 0; q < 64; q++) {
            float4 e = er[q];
            sm += expf(e.x - mx) + expf(e.y - mx) + expf(e.z - mx) + expf(e.w - mx);
        }
        ms[s] = mx; ssum[s] = sm;
    }
    __syncthreads();
    lw[tid]       = expf(E[tid * B_ + b]         - ms[tid])       / ssum[tid];
    lw[256 + tid] = expf(E[(256 + tid) * B_ + b] - ms[256 + tid]) / ssum[256 + tid];
    __syncthreads();
    float acc = 0.f;
    const __hip_bfloat16* ep = enc + (long)b * ENCSTRIDE + tid;
#pragma unroll 8
    for (int s = 0; s < S_; s++) acc += lw[s] * __bfloat162float(ep[s * H_]);
    out_ctx[(long)b * (TLEN_ * H_) + tid] = acc;
    hc[256 + tid] = acc;
    __syncthreads();
    if (tid < 64) {
        float a[DI_] = {0.f, 0.f, 0.f, 0.f, 0.f};
        for (int k = tid; k < 2 * H_; k += 64) {
            float v = hc[k];
#pragma unroll
            for (int m = 0; m < DI_; m++) a[m] += v * ww[m * (2 * H_) + k];
        }
#pragma unroll
        for (int m = 0; m < DI_; m++)
            for (int off = 32; off > 0; off >>= 1) a[m] += __shfl_down(a[m], off);
        if (tid == 0) {
            float t5[DI_];
#pragma unroll
            for (int m = 0; m < DI_; m++) t5[m] = tanhf(a[m] + bw[m]);
#pragma unroll
            for (int m2 = 0; m2 < DI_; m2++) {
                float o = bop[m2];
#pragma unroll
                for (int m = 0; m < DI_; m++) o += t5[m] * wop[m2 * DI_ + m];
                out0[(long)b * (TLEN_ * DI_) + m2] = o;
                pred[b * DI_ + m2] = o;
            }
        }
    }
}

// ---------------------------------------------------------------------------
extern "C" void kernel_launch(void* const* d_in, const int* in_sizes, int n_in,
                              void* d_out, int out_size, void* d_ws, size_t ws_size,
                              hipStream_t stream) {
    const float* srcs   = (const float*)d_in[0];
    const float* wih_e1 = (const float*)d_in[1];
    const float* whh_e1 = (const float*)d_in[2];
    const float* b_e1   = (const float*)d_in[3];
    const float* wih_e2 = (const float*)d_in[4];
    const float* whh_e2 = (const float*)d_in[5];
    const float* b_e2   = (const float*)d_in[6];
    const float* wdi    = (const float*)d_in[7];
    const float* bdi    = (const float*)d_in[8];
    const float* wih_d1 = (const float*)d_in[9];
    const float* whh_d1 = (const float*)d_in[10];
    const float* b_d1   = (const float*)d_in[11];
    const float* wih_d2 = (const float*)d_in[12];
    const float* whh_d2 = (const float*)d_in[13];
    const float* b_d2   = (const float*)d_in[14];
    const float* ww     = (const float*)d_in[15];
    const float* bw     = (const float*)d_in[16];
    const float* wop    = (const float*)d_in[17];
    const float* bop    = (const float*)d_in[18];

    float* ws = (float*)d_ws;
    __hip_bfloat16* ENCBF = (__hip_bfloat16*)d_ws;   // [256][512][256] bf16 = 16,777,216 float slots
    size_t o = 16777216;
    ushort4* PKE1B = (ushort4*)(ws + o); o += 131072; // whh_e1 packed bf16
    ushort4* PKH2B = (ushort4*)(ws + o); o += 131072; // whh_e2 packed bf16
    ushort4* PKD1B = (ushort4*)(ws + o); o += 131072; // whh_d1 packed bf16
    ushort4* PKD2B = (ushort4*)(ws + o); o += 131072; // wih_d2 packed bf16
    float4* PKX2 = (float4*)(ws + o); o += 262144;   // wih_e2 packed fp32
    float* H1G = ws + o; o += 2097152;               // [CHUNK][B][H] e1 chunk (single)
    float* X2G = ws + o; o += 8388608;               // [CHUNK*B][1024] wih_e2 @ e1
    float* C1C = ws + o; o += 65536;                 // layer-1 c carry
    float* H2C = ws + o; o += 65536;                 // layer-2 h carry / decoder h
    float* C2C = ws + o; o += 65536;                 // layer-2 c carry / decoder c
    float* EN  = ws + o; o += 131072;                // energies
    float* PRD = ws + o; o += 1280;
    float* WEF = ws + o; o += 5120;
    float* BEF = ws + o; o += 1024;

    float* OUT0 = (float*)d_out;
    float* OUT1 = OUT0 + (size_t)B_ * TLEN_ * DI_;   // context_enc base

    dim3 t256(256);

    init_kernel<<<dim3(8), t256, 0, stream>>>(PRD);

    packbf_kernel<<<dim3(256), t256, 0, stream>>>(whh_e1, PKE1B);
    packbf_kernel<<<dim3(256), t256, 0, stream>>>(whh_e2, PKH2B);
    packbf_kernel<<<dim3(256), t256, 0, stream>>>(whh_d1, PKD1B);
    packbf_kernel<<<dim3(256), t256, 0, stream>>>(wih_d2, PKD2B);
    pack_kernel<<<dim3(256), t256, 0, stream>>>(wih_e2, PKX2);
    weff_kernel<<<dim3(4), t256, 0, stream>>>(wih_d1, wdi, bdi, b_d1, WEF, BEF);

    // ---------------- encoder: 17 chunked launches (256 blocks) + 16 xproj ----------------
    for (int ci = 0; ci <= NCHUNK; ci++) {
        enc_chunk_kernel<<<dim3(256), dim3(1024), 0, stream>>>(
            ci, srcs, wih_e1, PKE1B, PKH2B, b_e1, b_e2,
            X2G, H1G, C1C, H2C, C2C, ENCBF);
        if (ci < NCHUNK) {
            xproj_kernel<<<dim3(256), dim3(512), 0, stream>>>(H1G, PKX2, X2G);
        }
    }
    // final states: h_enc = H2C, c_enc = C2C

    // ---------------- decoder: 32 steps x 2 launches ----------------
    for (int t = 0; t < TLEN_; t++) {
        dec_step_kernel<<<dim3(128), dim3(1024), 0, stream>>>(
            PRD, WEF, BEF, PKD1B, PKD2B, b_d2, H2C, C2C, ENCBF, EN);
        ctx_out_kernel<<<dim3(256), t256, 0, stream>>>(
            EN, ENCBF, H2C, ww, bw, wop, bop,
            OUT1 + (size_t)t * H_, OUT0 + (size_t)t * DI_, PRD);
    }
}

// Round 14
// 10342.361 us; speedup vs baseline: 1.1203x; 1.1203x over previous
//
#include <hip/hip_runtime.h>
#include <hip/hip_bf16.h>

#define B_    256
#define S_    512
#define H_    256
#define TLEN_ 32
#define DI_   5
#define ENCSTRIDE 131072   // S_*H_
#define CHUNK 32
#define NCHUNK 16          // S_/CHUNK
#define NB 2               // batches per encoder block (256 blocks -> all CUs)

__device__ __forceinline__ float bf2f(unsigned short v) {
    return __uint_as_float(((unsigned)v) << 16);
}
__device__ __forceinline__ unsigned short f2bf(float f) {
    __hip_bfloat16 h = __float2bfloat16(f);
    return *reinterpret_cast<unsigned short*>(&h);
}

// ---------------------------------------------------------------------------
// init: set decoder inp0 = ones
// ---------------------------------------------------------------------------
__global__ __launch_bounds__(256) void init_kernel(float* PRD) {
    int i = blockIdx.x * 256 + threadIdx.x;      // grid 8 -> 2048
    if (i < B_ * DI_) PRD[i] = 1.0f;
}

// ---------------------------------------------------------------------------
// pack a [1024][256] row-major weight into [k4][n] float4 layout (fp32):
// out[k4*1024 + n] = {w[n][4k4], w[n][4k4+1], w[n][4k4+2], w[n][4k4+3]}
// ---------------------------------------------------------------------------
__global__ __launch_bounds__(256) void pack_kernel(const float* __restrict__ m,
                                                   float4* __restrict__ out) {
    int idx = blockIdx.x * 256 + threadIdx.x;    // grid 256 -> 65536
    int k4 = idx >> 10, n = idx & 1023;
    out[idx] = ((const float4*)m)[n * 64 + k4];
}

// ---------------------------------------------------------------------------
// same pack, bf16 payload (ushort4 = 4 weights / 8B): halves weight streams.
// ---------------------------------------------------------------------------
__global__ __launch_bounds__(256) void packbf_kernel(const float* __restrict__ m,
                                                     ushort4* __restrict__ out) {
    int idx = blockIdx.x * 256 + threadIdx.x;    // grid 256 -> 65536
    int k4 = idx >> 10, n = idx & 1023;
    float4 v = ((const float4*)m)[n * 64 + k4];
    out[idx] = make_ushort4(f2bf(v.x), f2bf(v.y), f2bf(v.z), f2bf(v.w));
}

// ---------------------------------------------------------------------------
// Weff[n][m] = sum_k wih_d1[n][k]*wdi[k][m]; beff[n] = b_d1[n] + wih_d1[n]·bdi
// ---------------------------------------------------------------------------
__global__ __launch_bounds__(256) void weff_kernel(const float* __restrict__ wih_d1,
                                                   const float* __restrict__ wdi,
                                                   const float* __restrict__ bdi,
                                                   const float* __restrict__ b_d1,
                                                   float* __restrict__ weff,
                                                   float* __restrict__ beff) {
    int n = blockIdx.x * 256 + threadIdx.x;      // grid 4 -> 1024
    float acc[DI_] = {0.f, 0.f, 0.f, 0.f, 0.f};
    float accb = 0.f;
    for (int k = 0; k < H_; k++) {
        float w = wih_d1[n * H_ + k];
        accb += w * bdi[k];
#pragma unroll
        for (int m = 0; m < DI_; m++) acc[m] += w * wdi[k * DI_ + m];
    }
#pragma unroll
    for (int m = 0; m < DI_; m++) weff[n * DI_ + m] = acc[m];
    beff[n] = b_d1[n] + accb;
}

// ---------------------------------------------------------------------------
// dot-chunk helper: a0..a3 += xv · w{0..3}
// ---------------------------------------------------------------------------
__device__ __forceinline__ void dot4(const float4 xv, const float4 w0, const float4 w1,
                                     const float4 w2, const float4 w3,
                                     float& a0, float& a1, float& a2, float& a3) {
    a0 += xv.x * w0.x + xv.y * w0.y + xv.z * w0.z + xv.w * w0.w;
    a1 += xv.x * w1.x + xv.y * w1.y + xv.z * w1.z + xv.w * w1.w;
    a2 += xv.x * w2.x + xv.y * w2.y + xv.z * w2.z + xv.w * w2.w;
    a3 += xv.x * w3.x + xv.y * w3.y + xv.z * w3.z + xv.w * w3.w;
}

__device__ __forceinline__ float4 bf4f(ushort4 u) {
    return make_float4(bf2f(u.x), bf2f(u.y), bf2f(u.z), bf2f(u.w));
}

__device__ __forceinline__ void lstm_epilogue(float a0, float a1, float a2, float a3,
                                              float cold, float& cn, float& hn) {
    float ii = 1.f / (1.f + expf(-a0));
    float ff = 1.f / (1.f + expf(-a1));
    float gg = tanhf(a2);
    float oo = 1.f / (1.f + expf(-a3));
    cn = ff * cold + ii * gg;
    hn = oo * tanhf(cn);
}

// ---------------------------------------------------------------------------
// xproj (r10-proven v1): X2[u][b][n] = sum_k wih_e2[n][k] * e1[u][b][k].
// Weight-stationary; e1 broadcast from LDS.
// ---------------------------------------------------------------------------
__global__ __launch_bounds__(512) void xproj_kernel(
    const float* __restrict__ h1,      // [CHUNK][B_][H_]
    const float4* __restrict__ wp,     // packed [64][1024] (PKX2)
    float* __restrict__ X2)            // [CHUNK*B_][1024]
{
    __shared__ float es[16][260];      // 16 staged e1 rows
    __shared__ float red[8][16][64];   // [kh][row][nl]
    int tid = threadIdx.x;
    int nt = blockIdx.x & 15, rg = blockIdx.x >> 4;
    int nl = tid & 63, kh = tid >> 6;  // kh in [0,8)
    int n = nt * 64 + nl;

    float4 w[8];
#pragma unroll
    for (int q = 0; q < 8; q++) w[q] = wp[(((kh << 3) + q) << 10) + n];

    for (int rnd = 0; rnd < 32; rnd++) {
        int r0 = rg * 512 + rnd * 16;
        for (int i = tid; i < 1024; i += 512) {
            int rr = i >> 6, c4 = i & 63;
            ((float4*)&es[rr][0])[c4] = ((const float4*)(h1 + (long)(r0 + rr) * H_))[c4];
        }
        __syncthreads();
        float acc[16];
#pragma unroll
        for (int rr = 0; rr < 16; rr++) acc[rr] = 0.f;
#pragma unroll
        for (int q = 0; q < 8; q++) {
            float4 wq = w[q];
#pragma unroll
            for (int rr = 0; rr < 16; rr++) {
                float4 e = ((const float4*)&es[rr][0])[(kh << 3) + q];
                acc[rr] += e.x * wq.x + e.y * wq.y + e.z * wq.z + e.w * wq.w;
            }
        }
#pragma unroll
        for (int rr = 0; rr < 16; rr++) red[kh][rr][nl] = acc[rr];
        __syncthreads();
        for (int rr = kh; rr < 16; rr += 8) {
            float s = 0.f;
#pragma unroll
            for (int kk = 0; kk < 8; kk++) s += red[kk][rr][nl];
            X2[(long)(r0 + rr) * 1024 + n] = s;
        }
        __syncthreads();               // X2/red reads done before next stage
    }
}

// ---------------------------------------------------------------------------
// Chunked encoder NB=2 with BF16 recurrent weights (r12-proven):
// per-CU whh stream 0.5MB/step; r5 inner loops.
// ---------------------------------------------------------------------------
__global__ __launch_bounds__(1024, 4) void enc_chunk_kernel(
    int ci,
    const float* __restrict__ srcs,
    const float* __restrict__ wih_e1,      // [1024][5] raw
    const ushort4* __restrict__ whh_e1p,   // packed bf16 [64][1024]
    const ushort4* __restrict__ whh_e2p,   // packed bf16 [64][1024]
    const float* __restrict__ b_e1,
    const float* __restrict__ b_e2,
    const float* __restrict__ X2,          // [CHUNK*B_][1024] wih_e2 part
    float* __restrict__ H1G,               // [CHUNK][B_][H_] (single buffer)
    float* __restrict__ C1C,               // [B_][H_] layer-1 c carry
    float* __restrict__ H2C,               // [B_][H_] layer-2 h carry (final = h_enc)
    float* __restrict__ C2C,               // [B_][H_] layer-2 c carry (final = c_enc)
    __hip_bfloat16* __restrict__ encbf)    // [b][s][h]
{
    __shared__ float4 red[4][NB][256];     // [kh][bb][j] -> 4 gate partials, 32KB
    __shared__ float hb[NB][260];          // own-layer h (current step)
    __shared__ float sS[NB][160];          // L1 srcs chunk

    int tid = threadIdx.x;
    int kh = tid >> 8;                     // K-slice (accum); bb in reduce (kh<NB)
    int j  = tid & 255;
    int k40 = kh << 4;                     // 16 k4 iterations per slice

    if (blockIdx.x < 128) {
        // ================= layer 1, chunk ci =================
        if (ci >= NCHUNK) return;
        int b0 = blockIdx.x * NB;
        int ts = ci * CHUNK;

        for (int idx = tid; idx < NB * CHUNK * DI_; idx += 1024) {
            int r = idx / (CHUNK * DI_), off = idx - r * (CHUNK * DI_);
            sS[r][off] = srcs[((long)(b0 + r) * S_ + ts) * DI_ + off];
        }
        float creg = 0.f;
        if (kh < NB) {
            hb[kh][j] = (ci == 0) ? 0.f : H1G[(CHUNK - 1) * 65536 + (b0 + kh) * H_ + j];
            creg = (ci == 0) ? 0.f : C1C[(b0 + kh) * H_ + j];
        }
        float bias0 = b_e1[j], bias1 = b_e1[256 + j], bias2 = b_e1[512 + j], bias3 = b_e1[768 + j];
        float wx[4][DI_];
#pragma unroll
        for (int k = 0; k < DI_; k++) {
            wx[0][k] = wih_e1[j * DI_ + k];
            wx[1][k] = wih_e1[(256 + j) * DI_ + k];
            wx[2][k] = wih_e1[(512 + j) * DI_ + k];
            wx[3][k] = wih_e1[(768 + j) * DI_ + k];
        }

        for (int tt = 0; tt < CHUNK; tt++) {
            __syncthreads();               // hb ready; prev red reads done
            float A[NB][4];
#pragma unroll
            for (int bb = 0; bb < NB; bb++) {
                A[bb][0] = 0.f; A[bb][1] = 0.f; A[bb][2] = 0.f; A[bb][3] = 0.f;
            }
            if (kh == 0) {                 // input projection K=5 (wave-uniform branch)
#pragma unroll
                for (int bb = 0; bb < NB; bb++)
#pragma unroll
                    for (int k = 0; k < DI_; k++) {
                        float xv = sS[bb][tt * DI_ + k];
                        A[bb][0] += xv * wx[0][k];
                        A[bb][1] += xv * wx[1][k];
                        A[bb][2] += xv * wx[2][k];
                        A[bb][3] += xv * wx[3][k];
                    }
            }
#pragma unroll 4
            for (int k4 = k40; k4 < k40 + 16; k4++) {
                float4 w0 = bf4f(whh_e1p[(k4 << 10) + j]);
                float4 w1 = bf4f(whh_e1p[(k4 << 10) + 256 + j]);
                float4 w2 = bf4f(whh_e1p[(k4 << 10) + 512 + j]);
                float4 w3 = bf4f(whh_e1p[(k4 << 10) + 768 + j]);
#pragma unroll
                for (int bb = 0; bb < NB; bb++) {
                    float4 h4 = ((const float4*)&hb[bb][0])[k4];
                    dot4(h4, w0, w1, w2, w3, A[bb][0], A[bb][1], A[bb][2], A[bb][3]);
                }
            }
#pragma unroll
            for (int bb = 0; bb < NB; bb++)
                red[kh][bb][j] = make_float4(A[bb][0], A[bb][1], A[bb][2], A[bb][3]);
            __syncthreads();               // red complete; hb reads done
            if (kh < NB) {
                float a0 = bias0, a1 = bias1, a2 = bias2, a3 = bias3;
#pragma unroll
                for (int kk = 0; kk < 4; kk++) {
                    float4 v = red[kk][kh][j];
                    a0 += v.x; a1 += v.y; a2 += v.z; a3 += v.w;
                }
                float cn, hn;
                lstm_epilogue(a0, a1, a2, a3, creg, cn, hn);
                creg = cn;
                hb[kh][j] = hn;
                H1G[tt * 65536 + (b0 + kh) * H_ + j] = hn;
            }
        }
        if (kh < NB) C1C[(b0 + kh) * H_ + j] = creg;
    } else {
        // ================= layer 2, chunk ci-1 =================
        if (ci < 1) return;
        int b0 = (blockIdx.x - 128) * NB;
        int us = (ci - 1) * CHUNK;

        float creg = 0.f, hlast = 0.f;
        if (kh < NB) {
            hb[kh][j] = (ci == 1) ? 0.f : H2C[(b0 + kh) * H_ + j];
            creg = (ci == 1) ? 0.f : C2C[(b0 + kh) * H_ + j];
        }
        float bias0 = b_e2[j], bias1 = b_e2[256 + j], bias2 = b_e2[512 + j], bias3 = b_e2[768 + j];

        for (int tt = 0; tt < CHUNK; tt++) {
            __syncthreads();               // hb ready; prev red reads done
            float x0 = 0.f, x1 = 0.f, x2 = 0.f, x3 = 0.f;
            if (kh < NB) {                 // prefetch own X2 row (hidden under k4 loop)
                const float* xrow = X2 + ((long)tt * B_ + b0 + kh) * 1024;
                x0 = xrow[j]; x1 = xrow[256 + j]; x2 = xrow[512 + j]; x3 = xrow[768 + j];
            }
            float A[NB][4];
#pragma unroll
            for (int bb = 0; bb < NB; bb++) {
                A[bb][0] = 0.f; A[bb][1] = 0.f; A[bb][2] = 0.f; A[bb][3] = 0.f;
            }
#pragma unroll 4
            for (int k4 = k40; k4 < k40 + 16; k4++) {
                float4 w0 = bf4f(whh_e2p[(k4 << 10) + j]);
                float4 w1 = bf4f(whh_e2p[(k4 << 10) + 256 + j]);
                float4 w2 = bf4f(whh_e2p[(k4 << 10) + 512 + j]);
                float4 w3 = bf4f(whh_e2p[(k4 << 10) + 768 + j]);
#pragma unroll
                for (int bb = 0; bb < NB; bb++) {
                    float4 h4 = ((const float4*)&hb[bb][0])[k4];
                    dot4(h4, w0, w1, w2, w3, A[bb][0], A[bb][1], A[bb][2], A[bb][3]);
                }
            }
#pragma unroll
            for (int bb = 0; bb < NB; bb++)
                red[kh][bb][j] = make_float4(A[bb][0], A[bb][1], A[bb][2], A[bb][3]);
            __syncthreads();               // red complete; hb reads done
            if (kh < NB) {
                float a0 = bias0 + x0, a1 = bias1 + x1, a2 = bias2 + x2, a3 = bias3 + x3;
#pragma unroll
                for (int kk = 0; kk < 4; kk++) {
                    float4 v = red[kk][kh][j];
                    a0 += v.x; a1 += v.y; a2 += v.z; a3 += v.w;
                }
                float cn, hn;
                lstm_epilogue(a0, a1, a2, a3, creg, cn, hn);
                creg = cn;
                hlast = hn;
                hb[kh][j] = hn;
                encbf[(long)(b0 + kh) * ENCSTRIDE + (us + tt) * H_ + j] = __float2bfloat16(hn);
            }
        }
        if (kh < NB) {
            H2C[(b0 + kh) * H_ + j] = hlast;
            C2C[(b0 + kh) * H_ + j] = creg;
        }
    }
}

// ---------------------------------------------------------------------------
// Decoder step: cell1 + cell2 + energies in ONE launch. BF16 cell weights
// (r13-numerics-verified: absmax 9.8e-4). 128 blocks x 1024 threads.
// Energies: float2 loads, 4 bf16/lane (64 x 4 = 256 = H_).
// ---------------------------------------------------------------------------
__global__ __launch_bounds__(1024) void dec_step_kernel(
    const float* __restrict__ PRD,
    const float* __restrict__ WEF,       // [1024][5]
    const float* __restrict__ BEF,       // [1024]
    const ushort4* __restrict__ whhd1p,  // packed bf16 [64][1024]
    const ushort4* __restrict__ wihd2p,  // packed bf16 [64][1024]
    const float* __restrict__ b_d2,
    float* __restrict__ H2C,             // in: h2prev, out: h2new (own rows only)
    float* __restrict__ C2C,             // in: c2prev, out: c2new (own rows only)
    const __hip_bfloat16* __restrict__ enc,
    float* __restrict__ E)               // [S_][B_]
{
    __shared__ float h2s[2][260];        // h2prev
    __shared__ float h1s[2][260];
    __shared__ float h2n[2][260];        // h2 new
    __shared__ float g[2][1024];         // gate accum staging
    __shared__ float prd[2][8];
    int tid = threadIdx.x;
    int j = tid;
    int b0 = blockIdx.x * 2;

    if (tid < 512) h2s[tid >> 8][tid & 255] = H2C[(b0 + (tid >> 8)) * H_ + (tid & 255)];
    if (tid < 2 * DI_) prd[tid / DI_][tid % DI_] = PRD[(b0 + tid / DI_) * DI_ + tid % DI_];
    __syncthreads();

    // ---- phase A: cell1 gates ----
    {
        float wef[DI_];
#pragma unroll
        for (int m = 0; m < DI_; m++) wef[m] = WEF[j * DI_ + m];
        float be = BEF[j];
        float a[2];
#pragma unroll
        for (int bb = 0; bb < 2; bb++) {
            a[bb] = be;
#pragma unroll
            for (int m = 0; m < DI_; m++) a[bb] += wef[m] * prd[bb][m];
        }
#pragma unroll 4
        for (int k4 = 0; k4 < 64; k4++) {
            float4 w = bf4f(whhd1p[(k4 << 10) + j]);
#pragma unroll
            for (int bb = 0; bb < 2; bb++) {
                float4 h4 = ((const float4*)&h2s[bb][0])[k4];
                a[bb] += h4.x * w.x + h4.y * w.y + h4.z * w.z + h4.w * w.w;
            }
        }
        g[0][j] = a[0]; g[1][j] = a[1];
    }
    __syncthreads();
    if (tid < 512) {
        int bb = tid >> 8, n = tid & 255;
        float cn, hn;
        lstm_epilogue(g[bb][n], g[bb][256 + n], g[bb][512 + n], g[bb][768 + n],
                      C2C[(b0 + bb) * H_ + n], cn, hn);
        h1s[bb][n] = hn;                 // c1 is not carried
    }
    __syncthreads();

    // ---- phase B: cell2 gates (h=c=0, no whh) ----
    {
        float b2 = b_d2[j];
        float a[2] = {b2, b2};
#pragma unroll 4
        for (int k4 = 0; k4 < 64; k4++) {
            float4 w = bf4f(wihd2p[(k4 << 10) + j]);
#pragma unroll
            for (int bb = 0; bb < 2; bb++) {
                float4 h4 = ((const float4*)&h1s[bb][0])[k4];
                a[bb] += h4.x * w.x + h4.y * w.y + h4.z * w.z + h4.w * w.w;
            }
        }
        g[0][j] = a[0]; g[1][j] = a[1];
    }
    __syncthreads();
    if (tid < 512) {
        int bb = tid >> 8, n = tid & 255;
        float cn, hn;
        lstm_epilogue(g[bb][n], g[bb][256 + n], g[bb][512 + n], g[bb][768 + n],
                      0.f, cn, hn);
        C2C[(b0 + bb) * H_ + n] = cn;
        H2C[(b0 + bb) * H_ + n] = hn;
        h2n[bb][n] = hn;
    }
    __syncthreads();

    // ---- phase C: energies (4 bf16 per lane: 64 x 4 = 256 = H_) ----
    {
        int wv = tid >> 6, lane = tid & 63;
        int bb = wv >> 3, ws = wv & 7;
        const __hip_bfloat16* ep = enc + (long)(b0 + bb) * ENCSTRIDE;
        float hreg[4];
#pragma unroll
        for (int q = 0; q < 4; q++) hreg[q] = h2n[bb][(lane << 2) + q];
        for (int si = 0; si < 64; si++) {
            int s = ws + (si << 3);
            union { float2 f2; unsigned short u[4]; } uu;
            uu.f2 = *(const float2*)(ep + s * H_ + (lane << 2));
            float p = hreg[0] * bf2f(uu.u[0]) + hreg[1] * bf2f(uu.u[1]) +
                      hreg[2] * bf2f(uu.u[2]) + hreg[3] * bf2f(uu.u[3]);
#pragma unroll
            for (int off = 32; off > 0; off >>= 1) p += __shfl_down(p, off);
            if (lane == 0) E[s * B_ + b0 + bb] = p;
        }
    }
}

// ---------------------------------------------------------------------------
// softmax over batch (per s): W[s][b]      grid 512 x 256  (r10/r12-proven;
// three attempts to fuse this into neighbors all regressed -- keep it)
// ---------------------------------------------------------------------------
__global__ __launch_bounds__(256) void softmax_kernel(const float* __restrict__ E,
                                                      float* __restrict__ W) {
    __shared__ float red[4];
    int s = blockIdx.x, tid = threadIdx.x;
    float v = E[s * B_ + tid];
    float m = v;
#pragma unroll
    for (int off = 32; off > 0; off >>= 1) m = fmaxf(m, __shfl_down(m, off));
    if ((tid & 63) == 0) red[tid >> 6] = m;
    __syncthreads();
    m = fmaxf(fmaxf(red[0], red[1]), fmaxf(red[2], red[3]));
    __syncthreads();
    float e = expf(v - m);
    float p = e;
#pragma unroll
    for (int off = 32; off > 0; off >>= 1) p += __shfl_down(p, off);
    if ((tid & 63) == 0) red[tid >> 6] = p;
    __syncthreads();
    float sum = red[0] + red[1] + red[2] + red[3];
    W[s * B_ + tid] = e / sum;
}

// ---------------------------------------------------------------------------
// context + decout fused (r10-proven): block b computes ctx[b][:], then the
// 2H->DI_ and DI_->DI_ matvecs on wave 0.
// ---------------------------------------------------------------------------
__global__ __launch_bounds__(256) void ctx_out_kernel(
    const float* __restrict__ W,
    const __hip_bfloat16* __restrict__ enc,
    const float* __restrict__ h2,
    const float* __restrict__ ww, const float* __restrict__ bw,
    const float* __restrict__ wop, const float* __restrict__ bop,
    float* __restrict__ out_ctx,   // OUT1 + t*H_ pre-offset
    float* __restrict__ out0,      // OUT0 + t*DI_ pre-offset
    float* __restrict__ pred)
{
    __shared__ float lw[S_];
    __shared__ float hc[512];      // [h2 | ctx]
    int b = blockIdx.x, tid = threadIdx.x;
    lw[tid] = W[tid * B_ + b];
    lw[256 + tid] = W[(256 + tid) * B_ + b];
    hc[tid] = h2[b * H_ + tid];
    __syncthreads();
    float acc = 0.f;
    const __hip_bfloat16* ep = enc + (long)b * ENCSTRIDE + tid;
#pragma unroll 8
    for (int s = 0; s < S_; s++) acc += lw[s] * __bfloat162float(ep[s * H_]);
    out_ctx[(long)b * (TLEN_ * H_) + tid] = acc;
    hc[256 + tid] = acc;
    __syncthreads();
    if (tid < 64) {
        float a[DI_] = {0.f, 0.f, 0.f, 0.f, 0.f};
        for (int k = tid; k < 2 * H_; k += 64) {
            float v = hc[k];
#pragma unroll
            for (int m = 0; m < DI_; m++) a[m] += v * ww[m * (2 * H_) + k];
        }
#pragma unroll
        for (int m = 0; m < DI_; m++)
            for (int off = 32; off > 0; off >>= 1) a[m] += __shfl_down(a[m], off);
        if (tid == 0) {
            float t5[DI_];
#pragma unroll
            for (int m = 0; m < DI_; m++) t5[m] = tanhf(a[m] + bw[m]);
#pragma unroll
            for (int m2 = 0; m2 < DI_; m2++) {
                float o = bop[m2];
#pragma unroll
                for (int m = 0; m < DI_; m++) o += t5[m] * wop[m2 * DI_ + m];
                out0[(long)b * (TLEN_ * DI_) + m2] = o;
                pred[b * DI_ + m2] = o;
            }
        }
    }
}

// ---------------------------------------------------------------------------
extern "C" void kernel_launch(void* const* d_in, const int* in_sizes, int n_in,
                              void* d_out, int out_size, void* d_ws, size_t ws_size,
                              hipStream_t stream) {
    const float* srcs   = (const float*)d_in[0];
    const float* wih_e1 = (const float*)d_in[1];
    const float* whh_e1 = (const float*)d_in[2];
    const float* b_e1   = (const float*)d_in[3];
    const float* wih_e2 = (const float*)d_in[4];
    const float* whh_e2 = (const float*)d_in[5];
    const float* b_e2   = (const float*)d_in[6];
    const float* wdi    = (const float*)d_in[7];
    const float* bdi    = (const float*)d_in[8];
    const float* wih_d1 = (const float*)d_in[9];
    const float* whh_d1 = (const float*)d_in[10];
    const float* b_d1   = (const float*)d_in[11];
    const float* wih_d2 = (const float*)d_in[12];
    const float* whh_d2 = (const float*)d_in[13];
    const float* b_d2   = (const float*)d_in[14];
    const float* ww     = (const float*)d_in[15];
    const float* bw     = (const float*)d_in[16];
    const float* wop    = (const float*)d_in[17];
    const float* bop    = (const float*)d_in[18];

    float* ws = (float*)d_ws;
    __hip_bfloat16* ENCBF = (__hip_bfloat16*)d_ws;   // [256][512][256] bf16 = 16,777,216 float slots
    size_t o = 16777216;
    ushort4* PKE1B = (ushort4*)(ws + o); o += 131072; // whh_e1 packed bf16
    ushort4* PKH2B = (ushort4*)(ws + o); o += 131072; // whh_e2 packed bf16
    ushort4* PKD1B = (ushort4*)(ws + o); o += 131072; // whh_d1 packed bf16
    ushort4* PKD2B = (ushort4*)(ws + o); o += 131072; // wih_d2 packed bf16
    float4* PKX2 = (float4*)(ws + o); o += 262144;   // wih_e2 packed fp32
    float* H1G = ws + o; o += 2097152;               // [CHUNK][B][H] e1 chunk (single)
    float* X2G = ws + o; o += 8388608;               // [CHUNK*B][1024] wih_e2 @ e1
    float* C1C = ws + o; o += 65536;                 // layer-1 c carry
    float* H2C = ws + o; o += 65536;                 // layer-2 h carry / decoder h
    float* C2C = ws + o; o += 65536;                 // layer-2 c carry / decoder c
    float* EN  = ws + o; o += 131072;                // energies
    float* WSM = ws + o; o += 131072;                // softmax weights
    float* PRD = ws + o; o += 1280;
    float* WEF = ws + o; o += 5120;
    float* BEF = ws + o; o += 1024;

    float* OUT0 = (float*)d_out;
    float* OUT1 = OUT0 + (size_t)B_ * TLEN_ * DI_;   // context_enc base

    dim3 t256(256);

    init_kernel<<<dim3(8), t256, 0, stream>>>(PRD);

    packbf_kernel<<<dim3(256), t256, 0, stream>>>(whh_e1, PKE1B);
    packbf_kernel<<<dim3(256), t256, 0, stream>>>(whh_e2, PKH2B);
    packbf_kernel<<<dim3(256), t256, 0, stream>>>(whh_d1, PKD1B);
    packbf_kernel<<<dim3(256), t256, 0, stream>>>(wih_d2, PKD2B);
    pack_kernel<<<dim3(256), t256, 0, stream>>>(wih_e2, PKX2);
    weff_kernel<<<dim3(4), t256, 0, stream>>>(wih_d1, wdi, bdi, b_d1, WEF, BEF);

    // ---------------- encoder: 17 chunked launches (256 blocks) + 16 xproj ----------------
    for (int ci = 0; ci <= NCHUNK; ci++) {
        enc_chunk_kernel<<<dim3(256), dim3(1024), 0, stream>>>(
            ci, srcs, wih_e1, PKE1B, PKH2B, b_e1, b_e2,
            X2G, H1G, C1C, H2C, C2C, ENCBF);
        if (ci < NCHUNK) {
            xproj_kernel<<<dim3(256), dim3(512), 0, stream>>>(H1G, PKX2, X2G);
        }
    }
    // final states: h_enc = H2C, c_enc = C2C

    // ---------------- decoder: 32 steps x 3 launches (r12-proven shape) ----------------
    for (int t = 0; t < TLEN_; t++) {
        dec_step_kernel<<<dim3(128), dim3(1024), 0, stream>>>(
            PRD, WEF, BEF, PKD1B, PKD2B, b_d2, H2C, C2C, ENCBF, EN);
        softmax_kernel<<<dim3(512), t256, 0, stream>>>(EN, WSM);
        ctx_out_kernel<<<dim3(256), t256, 0, stream>>>(
            WSM, ENCBF, H2C, ww, bw, wop, bop,
            OUT1 + (size_t)t * H_, OUT0 + (size_t)t * DI_, PRD);
    }
}

// Round 15
// 8363.014 us; speedup vs baseline: 1.3854x; 1.2367x over previous
//
#include <hip/hip_runtime.h>
#include <hip/hip_bf16.h>

#define B_    256
#define S_    512
#define H_    256
#define TLEN_ 32
#define DI_   5
#define ENCSTRIDE 131072   // S_*H_
#define CHUNK 32
#define NCHUNK 16          // S_/CHUNK
#define NB 2               // batches per encoder block (256 blocks -> all CUs)

__device__ __forceinline__ float bf2f(unsigned short v) {
    return __uint_as_float(((unsigned)v) << 16);
}
__device__ __forceinline__ unsigned short f2bf(float f) {
    __hip_bfloat16 h = __float2bfloat16(f);
    return *reinterpret_cast<unsigned short*>(&h);
}

// ---------------------------------------------------------------------------
// init: set decoder inp0 = ones
// ---------------------------------------------------------------------------
__global__ __launch_bounds__(256) void init_kernel(float* PRD) {
    int i = blockIdx.x * 256 + threadIdx.x;      // grid 8 -> 2048
    if (i < B_ * DI_) PRD[i] = 1.0f;
}

// ---------------------------------------------------------------------------
// pack bf16 payload (ushort4 = 4 weights / 8B): [1024][256] -> [k4][n].
// out[k4*1024 + n] = bf16{w[n][4k4..4k4+3]}
// ---------------------------------------------------------------------------
__global__ __launch_bounds__(256) void packbf_kernel(const float* __restrict__ m,
                                                     ushort4* __restrict__ out) {
    int idx = blockIdx.x * 256 + threadIdx.x;    // grid 256 -> 65536
    int k4 = idx >> 10, n = idx & 1023;
    float4 v = ((const float4*)m)[n * 64 + k4];
    out[idx] = make_ushort4(f2bf(v.x), f2bf(v.y), f2bf(v.z), f2bf(v.w));
}

// ---------------------------------------------------------------------------
// Weff[n][m] = sum_k wih_d1[n][k]*wdi[k][m]; beff[n] = b_d1[n] + wih_d1[n]·bdi
// ---------------------------------------------------------------------------
__global__ __launch_bounds__(256) void weff_kernel(const float* __restrict__ wih_d1,
                                                   const float* __restrict__ wdi,
                                                   const float* __restrict__ bdi,
                                                   const float* __restrict__ b_d1,
                                                   float* __restrict__ weff,
                                                   float* __restrict__ beff) {
    int n = blockIdx.x * 256 + threadIdx.x;      // grid 4 -> 1024
    float acc[DI_] = {0.f, 0.f, 0.f, 0.f, 0.f};
    float accb = 0.f;
    for (int k = 0; k < H_; k++) {
        float w = wih_d1[n * H_ + k];
        accb += w * bdi[k];
#pragma unroll
        for (int m = 0; m < DI_; m++) acc[m] += w * wdi[k * DI_ + m];
    }
#pragma unroll
    for (int m = 0; m < DI_; m++) weff[n * DI_ + m] = acc[m];
    beff[n] = b_d1[n] + accb;
}

// ---------------------------------------------------------------------------
// dot-chunk helper: a0..a3 += xv · w{0..3}
// ---------------------------------------------------------------------------
__device__ __forceinline__ void dot4(const float4 xv, const float4 w0, const float4 w1,
                                     const float4 w2, const float4 w3,
                                     float& a0, float& a1, float& a2, float& a3) {
    a0 += xv.x * w0.x + xv.y * w0.y + xv.z * w0.z + xv.w * w0.w;
    a1 += xv.x * w1.x + xv.y * w1.y + xv.z * w1.z + xv.w * w1.w;
    a2 += xv.x * w2.x + xv.y * w2.y + xv.z * w2.z + xv.w * w2.w;
    a3 += xv.x * w3.x + xv.y * w3.y + xv.z * w3.z + xv.w * w3.w;
}

__device__ __forceinline__ float4 bf4f(ushort4 u) {
    return make_float4(bf2f(u.x), bf2f(u.y), bf2f(u.z), bf2f(u.w));
}

__device__ __forceinline__ void lstm_epilogue(float a0, float a1, float a2, float a3,
                                              float cold, float& cn, float& hn) {
    float ii = 1.f / (1.f + expf(-a0));
    float ff = 1.f / (1.f + expf(-a1));
    float gg = tanhf(a2);
    float oo = 1.f / (1.f + expf(-a3));
    cn = ff * cold + ii * gg;
    hn = oo * tanhf(cn);
}

// ---------------------------------------------------------------------------
// xproj v3 (barrier-free): X2[row][n] = sum_k wih_e2[n][k]*e1[row][k].
// Block owns 32 rows (grid 256 = 8192/32). ONE barrier total (v1 had 96:
// 32 rounds x 3 -- and xproj's VALU floor is 27us, so barriers were ~half).
// Thread j owns column n=j with acc[32] in registers (static unroll); rows
// broadcast from LDS (wave-uniform, conflict-free); weights bf16-packed
// (0.5MB/CU stream, coalesced by n).
// ---------------------------------------------------------------------------
__global__ __launch_bounds__(1024) void xproj_kernel(
    const float* __restrict__ h1,      // [CHUNK][B_][H_] = [8192][256]
    const ushort4* __restrict__ wpb,   // packed bf16 [64][1024] (PKX2B)
    float* __restrict__ X2)            // [8192][1024]
{
    __shared__ float es[32][260];      // 32 staged e1 rows
    int tid = threadIdx.x, j = tid;
    long r0 = (long)blockIdx.x * 32;

    for (int i = tid; i < 2048; i += 1024) {
        int rr = i >> 6, c4 = i & 63;
        ((float4*)&es[rr][0])[c4] = ((const float4*)(h1 + (r0 + rr) * H_))[c4];
    }
    __syncthreads();

    float acc[32];
#pragma unroll
    for (int r = 0; r < 32; r++) acc[r] = 0.f;
    for (int k4 = 0; k4 < 64; k4++) {
        float4 w = bf4f(wpb[(k4 << 10) + j]);
#pragma unroll
        for (int r = 0; r < 32; r++) {
            float4 h4 = ((const float4*)&es[r][0])[k4];
            acc[r] += h4.x * w.x + h4.y * w.y + h4.z * w.z + h4.w * w.w;
        }
    }
#pragma unroll
    for (int r = 0; r < 32; r++) X2[(r0 + r) * 1024 + j] = acc[r];
}

// ---------------------------------------------------------------------------
// Chunked encoder NB=2 with BF16 recurrent weights (r12-proven):
// per-CU whh stream 0.5MB/step; r5 inner loops.
// ---------------------------------------------------------------------------
__global__ __launch_bounds__(1024, 4) void enc_chunk_kernel(
    int ci,
    const float* __restrict__ srcs,
    const float* __restrict__ wih_e1,      // [1024][5] raw
    const ushort4* __restrict__ whh_e1p,   // packed bf16 [64][1024]
    const ushort4* __restrict__ whh_e2p,   // packed bf16 [64][1024]
    const float* __restrict__ b_e1,
    const float* __restrict__ b_e2,
    const float* __restrict__ X2,          // [CHUNK*B_][1024] wih_e2 part
    float* __restrict__ H1G,               // [CHUNK][B_][H_] (single buffer)
    float* __restrict__ C1C,               // [B_][H_] layer-1 c carry
    float* __restrict__ H2C,               // [B_][H_] layer-2 h carry (final = h_enc)
    float* __restrict__ C2C,               // [B_][H_] layer-2 c carry (final = c_enc)
    __hip_bfloat16* __restrict__ encbf)    // [b][s][h]
{
    __shared__ float4 red[4][NB][256];     // [kh][bb][j] -> 4 gate partials, 32KB
    __shared__ float hb[NB][260];          // own-layer h (current step)
    __shared__ float sS[NB][160];          // L1 srcs chunk

    int tid = threadIdx.x;
    int kh = tid >> 8;                     // K-slice (accum); bb in reduce (kh<NB)
    int j  = tid & 255;
    int k40 = kh << 4;                     // 16 k4 iterations per slice

    if (blockIdx.x < 128) {
        // ================= layer 1, chunk ci =================
        if (ci >= NCHUNK) return;
        int b0 = blockIdx.x * NB;
        int ts = ci * CHUNK;

        for (int idx = tid; idx < NB * CHUNK * DI_; idx += 1024) {
            int r = idx / (CHUNK * DI_), off = idx - r * (CHUNK * DI_);
            sS[r][off] = srcs[((long)(b0 + r) * S_ + ts) * DI_ + off];
        }
        float creg = 0.f;
        if (kh < NB) {
            hb[kh][j] = (ci == 0) ? 0.f : H1G[(CHUNK - 1) * 65536 + (b0 + kh) * H_ + j];
            creg = (ci == 0) ? 0.f : C1C[(b0 + kh) * H_ + j];
        }
        float bias0 = b_e1[j], bias1 = b_e1[256 + j], bias2 = b_e1[512 + j], bias3 = b_e1[768 + j];
        float wx[4][DI_];
#pragma unroll
        for (int k = 0; k < DI_; k++) {
            wx[0][k] = wih_e1[j * DI_ + k];
            wx[1][k] = wih_e1[(256 + j) * DI_ + k];
            wx[2][k] = wih_e1[(512 + j) * DI_ + k];
            wx[3][k] = wih_e1[(768 + j) * DI_ + k];
        }

        for (int tt = 0; tt < CHUNK; tt++) {
            __syncthreads();               // hb ready; prev red reads done
            float A[NB][4];
#pragma unroll
            for (int bb = 0; bb < NB; bb++) {
                A[bb][0] = 0.f; A[bb][1] = 0.f; A[bb][2] = 0.f; A[bb][3] = 0.f;
            }
            if (kh == 0) {                 // input projection K=5 (wave-uniform branch)
#pragma unroll
                for (int bb = 0; bb < NB; bb++)
#pragma unroll
                    for (int k = 0; k < DI_; k++) {
                        float xv = sS[bb][tt * DI_ + k];
                        A[bb][0] += xv * wx[0][k];
                        A[bb][1] += xv * wx[1][k];
                        A[bb][2] += xv * wx[2][k];
                        A[bb][3] += xv * wx[3][k];
                    }
            }
#pragma unroll 4
            for (int k4 = k40; k4 < k40 + 16; k4++) {
                float4 w0 = bf4f(whh_e1p[(k4 << 10) + j]);
                float4 w1 = bf4f(whh_e1p[(k4 << 10) + 256 + j]);
                float4 w2 = bf4f(whh_e1p[(k4 << 10) + 512 + j]);
                float4 w3 = bf4f(whh_e1p[(k4 << 10) + 768 + j]);
#pragma unroll
                for (int bb = 0; bb < NB; bb++) {
                    float4 h4 = ((const float4*)&hb[bb][0])[k4];
                    dot4(h4, w0, w1, w2, w3, A[bb][0], A[bb][1], A[bb][2], A[bb][3]);
                }
            }
#pragma unroll
            for (int bb = 0; bb < NB; bb++)
                red[kh][bb][j] = make_float4(A[bb][0], A[bb][1], A[bb][2], A[bb][3]);
            __syncthreads();               // red complete; hb reads done
            if (kh < NB) {
                float a0 = bias0, a1 = bias1, a2 = bias2, a3 = bias3;
#pragma unroll
                for (int kk = 0; kk < 4; kk++) {
                    float4 v = red[kk][kh][j];
                    a0 += v.x; a1 += v.y; a2 += v.z; a3 += v.w;
                }
                float cn, hn;
                lstm_epilogue(a0, a1, a2, a3, creg, cn, hn);
                creg = cn;
                hb[kh][j] = hn;
                H1G[tt * 65536 + (b0 + kh) * H_ + j] = hn;
            }
        }
        if (kh < NB) C1C[(b0 + kh) * H_ + j] = creg;
    } else {
        // ================= layer 2, chunk ci-1 =================
        if (ci < 1) return;
        int b0 = (blockIdx.x - 128) * NB;
        int us = (ci - 1) * CHUNK;

        float creg = 0.f, hlast = 0.f;
        if (kh < NB) {
            hb[kh][j] = (ci == 1) ? 0.f : H2C[(b0 + kh) * H_ + j];
            creg = (ci == 1) ? 0.f : C2C[(b0 + kh) * H_ + j];
        }
        float bias0 = b_e2[j], bias1 = b_e2[256 + j], bias2 = b_e2[512 + j], bias3 = b_e2[768 + j];

        for (int tt = 0; tt < CHUNK; tt++) {
            __syncthreads();               // hb ready; prev red reads done
            float x0 = 0.f, x1 = 0.f, x2 = 0.f, x3 = 0.f;
            if (kh < NB) {                 // prefetch own X2 row (hidden under k4 loop)
                const float* xrow = X2 + ((long)tt * B_ + b0 + kh) * 1024;
                x0 = xrow[j]; x1 = xrow[256 + j]; x2 = xrow[512 + j]; x3 = xrow[768 + j];
            }
            float A[NB][4];
#pragma unroll
            for (int bb = 0; bb < NB; bb++) {
                A[bb][0] = 0.f; A[bb][1] = 0.f; A[bb][2] = 0.f; A[bb][3] = 0.f;
            }
#pragma unroll 4
            for (int k4 = k40; k4 < k40 + 16; k4++) {
                float4 w0 = bf4f(whh_e2p[(k4 << 10) + j]);
                float4 w1 = bf4f(whh_e2p[(k4 << 10) + 256 + j]);
                float4 w2 = bf4f(whh_e2p[(k4 << 10) + 512 + j]);
                float4 w3 = bf4f(whh_e2p[(k4 << 10) + 768 + j]);
#pragma unroll
                for (int bb = 0; bb < NB; bb++) {
                    float4 h4 = ((const float4*)&hb[bb][0])[k4];
                    dot4(h4, w0, w1, w2, w3, A[bb][0], A[bb][1], A[bb][2], A[bb][3]);
                }
            }
#pragma unroll
            for (int bb = 0; bb < NB; bb++)
                red[kh][bb][j] = make_float4(A[bb][0], A[bb][1], A[bb][2], A[bb][3]);
            __syncthreads();               // red complete; hb reads done
            if (kh < NB) {
                float a0 = bias0 + x0, a1 = bias1 + x1, a2 = bias2 + x2, a3 = bias3 + x3;
#pragma unroll
                for (int kk = 0; kk < 4; kk++) {
                    float4 v = red[kk][kh][j];
                    a0 += v.x; a1 += v.y; a2 += v.z; a3 += v.w;
                }
                float cn, hn;
                lstm_epilogue(a0, a1, a2, a3, creg, cn, hn);
                creg = cn;
                hlast = hn;
                hb[kh][j] = hn;
                encbf[(long)(b0 + kh) * ENCSTRIDE + (us + tt) * H_ + j] = __float2bfloat16(hn);
            }
        }
        if (kh < NB) {
            H2C[(b0 + kh) * H_ + j] = hlast;
            C2C[(b0 + kh) * H_ + j] = creg;
        }
    }
}

// ---------------------------------------------------------------------------
// Decoder step v2: 256 blocks x 1024 threads, ONE batch per block (v1 used
// 128 blocks = half the machine idle). Per-batch math and summation order
// identical. BF16 cell weights (r13/r14-numerics-verified).
// Energies: 16 waves x 32 s-values each; float2 loads, 4 bf16/lane.
// ---------------------------------------------------------------------------
__global__ __launch_bounds__(1024) void dec_step_kernel(
    const float* __restrict__ PRD,
    const float* __restrict__ WEF,       // [1024][5]
    const float* __restrict__ BEF,       // [1024]
    const ushort4* __restrict__ whhd1p,  // packed bf16 [64][1024]
    const ushort4* __restrict__ wihd2p,  // packed bf16 [64][1024]
    const float* __restrict__ b_d2,
    float* __restrict__ H2C,             // in: h2prev, out: h2new (own row only)
    float* __restrict__ C2C,             // in: c2prev, out: c2new (own row only)
    const __hip_bfloat16* __restrict__ enc,
    float* __restrict__ E)               // [S_][B_]
{
    __shared__ float h2s[260];           // h2prev
    __shared__ float h1s[260];
    __shared__ float h2n[260];           // h2 new
    __shared__ float g[1024];            // gate accum staging
    __shared__ float prd[8];
    int tid = threadIdx.x;
    int j = tid;
    int b = blockIdx.x;

    if (tid < 256) h2s[tid] = H2C[b * H_ + tid];
    if (tid < DI_) prd[tid] = PRD[b * DI_ + tid];
    __syncthreads();

    // ---- phase A: cell1 gates ----
    {
        float wef[DI_];
#pragma unroll
        for (int m = 0; m < DI_; m++) wef[m] = WEF[j * DI_ + m];
        float a = BEF[j];
#pragma unroll
        for (int m = 0; m < DI_; m++) a += wef[m] * prd[m];
#pragma unroll 4
        for (int k4 = 0; k4 < 64; k4++) {
            float4 w = bf4f(whhd1p[(k4 << 10) + j]);
            float4 h4 = ((const float4*)&h2s[0])[k4];
            a += h4.x * w.x + h4.y * w.y + h4.z * w.z + h4.w * w.w;
        }
        g[j] = a;
    }
    __syncthreads();
    if (tid < 256) {
        int n = tid;
        float cn, hn;
        lstm_epilogue(g[n], g[256 + n], g[512 + n], g[768 + n],
                      C2C[b * H_ + n], cn, hn);
        h1s[n] = hn;                     // c1 is not carried
    }
    __syncthreads();

    // ---- phase B: cell2 gates (h=c=0, no whh) ----
    {
        float a = b_d2[j];
#pragma unroll 4
        for (int k4 = 0; k4 < 64; k4++) {
            float4 w = bf4f(wihd2p[(k4 << 10) + j]);
            float4 h4 = ((const float4*)&h1s[0])[k4];
            a += h4.x * w.x + h4.y * w.y + h4.z * w.z + h4.w * w.w;
        }
        g[j] = a;
    }
    __syncthreads();
    if (tid < 256) {
        int n = tid;
        float cn, hn;
        lstm_epilogue(g[n], g[256 + n], g[512 + n], g[768 + n], 0.f, cn, hn);
        C2C[b * H_ + n] = cn;
        H2C[b * H_ + n] = hn;
        h2n[n] = hn;
    }
    __syncthreads();

    // ---- phase C: energies (16 waves x 32 s; 4 bf16/lane = 256 = H_) ----
    {
        int wv = tid >> 6, lane = tid & 63;
        const __hip_bfloat16* ep = enc + (long)b * ENCSTRIDE;
        float hreg[4];
#pragma unroll
        for (int q = 0; q < 4; q++) hreg[q] = h2n[(lane << 2) + q];
        for (int si = 0; si < 32; si++) {
            int s = wv + (si << 4);
            union { float2 f2; unsigned short u[4]; } uu;
            uu.f2 = *(const float2*)(ep + s * H_ + (lane << 2));
            float p = hreg[0] * bf2f(uu.u[0]) + hreg[1] * bf2f(uu.u[1]) +
                      hreg[2] * bf2f(uu.u[2]) + hreg[3] * bf2f(uu.u[3]);
#pragma unroll
            for (int off = 32; off > 0; off >>= 1) p += __shfl_down(p, off);
            if (lane == 0) E[s * B_ + b] = p;
        }
    }
}

// ---------------------------------------------------------------------------
// softmax over batch (per s): W[s][b]      grid 512 x 256  (proven; three
// attempts to fuse this into neighbors all regressed -- keep it)
// ---------------------------------------------------------------------------
__global__ __launch_bounds__(256) void softmax_kernel(const float* __restrict__ E,
                                                      float* __restrict__ W) {
    __shared__ float red[4];
    int s = blockIdx.x, tid = threadIdx.x;
    float v = E[s * B_ + tid];
    float m = v;
#pragma unroll
    for (int off = 32; off > 0; off >>= 1) m = fmaxf(m, __shfl_down(m, off));
    if ((tid & 63) == 0) red[tid >> 6] = m;
    __syncthreads();
    m = fmaxf(fmaxf(red[0], red[1]), fmaxf(red[2], red[3]));
    __syncthreads();
    float e = expf(v - m);
    float p = e;
#pragma unroll
    for (int off = 32; off > 0; off >>= 1) p += __shfl_down(p, off);
    if ((tid & 63) == 0) red[tid >> 6] = p;
    __syncthreads();
    float sum = red[0] + red[1] + red[2] + red[3];
    W[s * B_ + tid] = e / sum;
}

// ---------------------------------------------------------------------------
// context + decout fused (proven): block b computes ctx[b][:], then the
// 2H->DI_ and DI_->DI_ matvecs on wave 0.
// ---------------------------------------------------------------------------
__global__ __launch_bounds__(256) void ctx_out_kernel(
    const float* __restrict__ W,
    const __hip_bfloat16* __restrict__ enc,
    const float* __restrict__ h2,
    const float* __restrict__ ww, const float* __restrict__ bw,
    const float* __restrict__ wop, const float* __restrict__ bop,
    float* __restrict__ out_ctx,   // OUT1 + t*H_ pre-offset
    float* __restrict__ out0,      // OUT0 + t*DI_ pre-offset
    float* __restrict__ pred)
{
    __shared__ float lw[S_];
    __shared__ float hc[512];      // [h2 | ctx]
    int b = blockIdx.x, tid = threadIdx.x;
    lw[tid] = W[tid * B_ + b];
    lw[256 + tid] = W[(256 + tid) * B_ + b];
    hc[tid] = h2[b * H_ + tid];
    __syncthreads();
    float acc = 0.f;
    const __hip_bfloat16* ep = enc + (long)b * ENCSTRIDE + tid;
#pragma unroll 8
    for (int s = 0; s < S_; s++) acc += lw[s] * __bfloat162float(ep[s * H_]);
    out_ctx[(long)b * (TLEN_ * H_) + tid] = acc;
    hc[256 + tid] = acc;
    __syncthreads();
    if (tid < 64) {
        float a[DI_] = {0.f, 0.f, 0.f, 0.f, 0.f};
        for (int k = tid; k < 2 * H_; k += 64) {
            float v = hc[k];
#pragma unroll
            for (int m = 0; m < DI_; m++) a[m] += v * ww[m * (2 * H_) + k];
        }
#pragma unroll
        for (int m = 0; m < DI_; m++)
            for (int off = 32; off > 0; off >>= 1) a[m] += __shfl_down(a[m], off);
        if (tid == 0) {
            float t5[DI_];
#pragma unroll
            for (int m = 0; m < DI_; m++) t5[m] = tanhf(a[m] + bw[m]);
#pragma unroll
            for (int m2 = 0; m2 < DI_; m2++) {
                float o = bop[m2];
#pragma unroll
                for (int m = 0; m < DI_; m++) o += t5[m] * wop[m2 * DI_ + m];
                out0[(long)b * (TLEN_ * DI_) + m2] = o;
                pred[b * DI_ + m2] = o;
            }
        }
    }
}

// ---------------------------------------------------------------------------
extern "C" void kernel_launch(void* const* d_in, const int* in_sizes, int n_in,
                              void* d_out, int out_size, void* d_ws, size_t ws_size,
                              hipStream_t stream) {
    const float* srcs   = (const float*)d_in[0];
    const float* wih_e1 = (const float*)d_in[1];
    const float* whh_e1 = (const float*)d_in[2];
    const float* b_e1   = (const float*)d_in[3];
    const float* wih_e2 = (const float*)d_in[4];
    const float* whh_e2 = (const float*)d_in[5];
    const float* b_e2   = (const float*)d_in[6];
    const float* wdi    = (const float*)d_in[7];
    const float* bdi    = (const float*)d_in[8];
    const float* wih_d1 = (const float*)d_in[9];
    const float* whh_d1 = (const float*)d_in[10];
    const float* b_d1   = (const float*)d_in[11];
    const float* wih_d2 = (const float*)d_in[12];
    const float* whh_d2 = (const float*)d_in[13];
    const float* b_d2   = (const float*)d_in[14];
    const float* ww     = (const float*)d_in[15];
    const float* bw     = (const float*)d_in[16];
    const float* wop    = (const float*)d_in[17];
    const float* bop    = (const float*)d_in[18];

    float* ws = (float*)d_ws;
    __hip_bfloat16* ENCBF = (__hip_bfloat16*)d_ws;   // [256][512][256] bf16 = 16,777,216 float slots
    size_t o = 16777216;
    ushort4* PKE1B = (ushort4*)(ws + o); o += 131072; // whh_e1 packed bf16
    ushort4* PKH2B = (ushort4*)(ws + o); o += 131072; // whh_e2 packed bf16
    ushort4* PKD1B = (ushort4*)(ws + o); o += 131072; // whh_d1 packed bf16
    ushort4* PKD2B = (ushort4*)(ws + o); o += 131072; // wih_d2 packed bf16
    ushort4* PKX2B = (ushort4*)(ws + o); o += 131072; // wih_e2 packed bf16
    float* H1G = ws + o; o += 2097152;               // [CHUNK][B][H] e1 chunk (single)
    float* X2G = ws + o; o += 8388608;               // [CHUNK*B][1024] wih_e2 @ e1
    float* C1C = ws + o; o += 65536;                 // layer-1 c carry
    float* H2C = ws + o; o += 65536;                 // layer-2 h carry / decoder h
    float* C2C = ws + o; o += 65536;                 // layer-2 c carry / decoder c
    float* EN  = ws + o; o += 131072;                // energies
    float* WSM = ws + o; o += 131072;                // softmax weights
    float* PRD = ws + o; o += 1280;
    float* WEF = ws + o; o += 5120;
    float* BEF = ws + o; o += 1024;

    float* OUT0 = (float*)d_out;
    float* OUT1 = OUT0 + (size_t)B_ * TLEN_ * DI_;   // context_enc base

    dim3 t256(256);

    init_kernel<<<dim3(8), t256, 0, stream>>>(PRD);

    packbf_kernel<<<dim3(256), t256, 0, stream>>>(whh_e1, PKE1B);
    packbf_kernel<<<dim3(256), t256, 0, stream>>>(whh_e2, PKH2B);
    packbf_kernel<<<dim3(256), t256, 0, stream>>>(whh_d1, PKD1B);
    packbf_kernel<<<dim3(256), t256, 0, stream>>>(wih_d2, PKD2B);
    packbf_kernel<<<dim3(256), t256, 0, stream>>>(wih_e2, PKX2B);
    weff_kernel<<<dim3(4), t256, 0, stream>>>(wih_d1, wdi, bdi, b_d1, WEF, BEF);

    // ---------------- encoder: 17 chunked launches (256 blocks) + 16 xproj ----------------
    for (int ci = 0; ci <= NCHUNK; ci++) {
        enc_chunk_kernel<<<dim3(256), dim3(1024), 0, stream>>>(
            ci, srcs, wih_e1, PKE1B, PKH2B, b_e1, b_e2,
            X2G, H1G, C1C, H2C, C2C, ENCBF);
        if (ci < NCHUNK) {
            xproj_kernel<<<dim3(256), dim3(1024), 0, stream>>>(H1G, PKX2B, X2G);
        }
    }
    // final states: h_enc = H2C, c_enc = C2C

    // ---------------- decoder: 32 steps x 3 launches ----------------
    for (int t = 0; t < TLEN_; t++) {
        dec_step_kernel<<<dim3(256), dim3(1024), 0, stream>>>(
            PRD, WEF, BEF, PKD1B, PKD2B, b_d2, H2C, C2C, ENCBF, EN);
        softmax_kernel<<<dim3(512), t256, 0, stream>>>(EN, WSM);
        ctx_out_kernel<<<dim3(256), t256, 0, stream>>>(
            WSM, ENCBF, H2C, ww, bw, wop, bop,
            OUT1 + (size_t)t * H_, OUT0 + (size_t)t * DI_, PRD);
    }
}

// Round 16
// 7927.544 us; speedup vs baseline: 1.4615x; 1.0549x over previous
//
#include <hip/hip_runtime.h>
#include <hip/hip_bf16.h>

#define B_    256
#define S_    512
#define H_    256
#define TLEN_ 32
#define DI_   5
#define ENCSTRIDE 131072   // S_*H_
#define CHUNK 32
#define NCHUNK 16          // S_/CHUNK
#define NB 2               // batches per encoder block (256 blocks -> all CUs)

__device__ __forceinline__ float bf2f(unsigned short v) {
    return __uint_as_float(((unsigned)v) << 16);
}
__device__ __forceinline__ unsigned short f2bf(float f) {
    __hip_bfloat16 h = __float2bfloat16(f);
    return *reinterpret_cast<unsigned short*>(&h);
}

// ---------------------------------------------------------------------------
// init: set decoder inp0 = ones
// ---------------------------------------------------------------------------
__global__ __launch_bounds__(256) void init_kernel(float* PRD) {
    int i = blockIdx.x * 256 + threadIdx.x;      // grid 8 -> 2048
    if (i < B_ * DI_) PRD[i] = 1.0f;
}

// ---------------------------------------------------------------------------
// pack bf16 payload (ushort4 = 4 weights / 8B): [1024][256] -> [k4][n].
// ---------------------------------------------------------------------------
__global__ __launch_bounds__(256) void packbf_kernel(const float* __restrict__ m,
                                                     ushort4* __restrict__ out) {
    int idx = blockIdx.x * 256 + threadIdx.x;    // grid 256 -> 65536
    int k4 = idx >> 10, n = idx & 1023;
    float4 v = ((const float4*)m)[n * 64 + k4];
    out[idx] = make_ushort4(f2bf(v.x), f2bf(v.y), f2bf(v.z), f2bf(v.w));
}

// ---------------------------------------------------------------------------
// Weff[n][m] = sum_k wih_d1[n][k]*wdi[k][m]; beff[n] = b_d1[n] + wih_d1[n]·bdi
// ---------------------------------------------------------------------------
__global__ __launch_bounds__(256) void weff_kernel(const float* __restrict__ wih_d1,
                                                   const float* __restrict__ wdi,
                                                   const float* __restrict__ bdi,
                                                   const float* __restrict__ b_d1,
                                                   float* __restrict__ weff,
                                                   float* __restrict__ beff) {
    int n = blockIdx.x * 256 + threadIdx.x;      // grid 4 -> 1024
    float acc[DI_] = {0.f, 0.f, 0.f, 0.f, 0.f};
    float accb = 0.f;
    for (int k = 0; k < H_; k++) {
        float w = wih_d1[n * H_ + k];
        accb += w * bdi[k];
#pragma unroll
        for (int m = 0; m < DI_; m++) acc[m] += w * wdi[k * DI_ + m];
    }
#pragma unroll
    for (int m = 0; m < DI_; m++) weff[n * DI_ + m] = acc[m];
    beff[n] = b_d1[n] + accb;
}

// ---------------------------------------------------------------------------
// dot-chunk helper: a0..a3 += xv · w{0..3}
// ---------------------------------------------------------------------------
__device__ __forceinline__ void dot4(const float4 xv, const float4 w0, const float4 w1,
                                     const float4 w2, const float4 w3,
                                     float& a0, float& a1, float& a2, float& a3) {
    a0 += xv.x * w0.x + xv.y * w0.y + xv.z * w0.z + xv.w * w0.w;
    a1 += xv.x * w1.x + xv.y * w1.y + xv.z * w1.z + xv.w * w1.w;
    a2 += xv.x * w2.x + xv.y * w2.y + xv.z * w2.z + xv.w * w2.w;
    a3 += xv.x * w3.x + xv.y * w3.y + xv.z * w3.z + xv.w * w3.w;
}

__device__ __forceinline__ float4 bf4f(ushort4 u) {
    return make_float4(bf2f(u.x), bf2f(u.y), bf2f(u.z), bf2f(u.w));
}

__device__ __forceinline__ void lstm_epilogue(float a0, float a1, float a2, float a3,
                                              float cold, float& cn, float& hn) {
    float ii = 1.f / (1.f + expf(-a0));
    float ff = 1.f / (1.f + expf(-a1));
    float gg = tanhf(a2);
    float oo = 1.f / (1.f + expf(-a3));
    cn = ff * cold + ii * gg;
    hn = oo * tanhf(cn);
}

// ---------------------------------------------------------------------------
// xproj v3 (barrier-free, r15-proven): X2[row][n] = sum_k wih_e2[n][k]*e1[row][k].
// ---------------------------------------------------------------------------
__global__ __launch_bounds__(1024) void xproj_kernel(
    const float* __restrict__ h1,      // [CHUNK][B_][H_] = [8192][256]
    const ushort4* __restrict__ wpb,   // packed bf16 [64][1024] (PKX2B)
    float* __restrict__ X2)            // [8192][1024]
{
    __shared__ float es[32][260];      // 32 staged e1 rows
    int tid = threadIdx.x, j = tid;
    long r0 = (long)blockIdx.x * 32;

    for (int i = tid; i < 2048; i += 1024) {
        int rr = i >> 6, c4 = i & 63;
        ((float4*)&es[rr][0])[c4] = ((const float4*)(h1 + (r0 + rr) * H_))[c4];
    }
    __syncthreads();

    float acc[32];
#pragma unroll
    for (int r = 0; r < 32; r++) acc[r] = 0.f;
    for (int k4 = 0; k4 < 64; k4++) {
        float4 w = bf4f(wpb[(k4 << 10) + j]);
#pragma unroll
        for (int r = 0; r < 32; r++) {
            float4 h4 = ((const float4*)&es[r][0])[k4];
            acc[r] += h4.x * w.x + h4.y * w.y + h4.z * w.z + h4.w * w.w;
        }
    }
#pragma unroll
    for (int r = 0; r < 32; r++) X2[(r0 + r) * 1024 + j] = acc[r];
}

// ---------------------------------------------------------------------------
// Chunked encoder NB=2 with BF16 recurrent weights (r12/r15-proven).
// ---------------------------------------------------------------------------
__global__ __launch_bounds__(1024, 4) void enc_chunk_kernel(
    int ci,
    const float* __restrict__ srcs,
    const float* __restrict__ wih_e1,      // [1024][5] raw
    const ushort4* __restrict__ whh_e1p,   // packed bf16 [64][1024]
    const ushort4* __restrict__ whh_e2p,   // packed bf16 [64][1024]
    const float* __restrict__ b_e1,
    const float* __restrict__ b_e2,
    const float* __restrict__ X2,          // [CHUNK*B_][1024] wih_e2 part
    float* __restrict__ H1G,               // [CHUNK][B_][H_] (single buffer)
    float* __restrict__ C1C,               // [B_][H_] layer-1 c carry
    float* __restrict__ H2C,               // [B_][H_] layer-2 h carry (final = h_enc)
    float* __restrict__ C2C,               // [B_][H_] layer-2 c carry (final = c_enc)
    __hip_bfloat16* __restrict__ encbf)    // [b][s][h]
{
    __shared__ float4 red[4][NB][256];     // [kh][bb][j] -> 4 gate partials, 32KB
    __shared__ float hb[NB][260];          // own-layer h (current step)
    __shared__ float sS[NB][160];          // L1 srcs chunk

    int tid = threadIdx.x;
    int kh = tid >> 8;                     // K-slice (accum); bb in reduce (kh<NB)
    int j  = tid & 255;
    int k40 = kh << 4;                     // 16 k4 iterations per slice

    if (blockIdx.x < 128) {
        // ================= layer 1, chunk ci =================
        if (ci >= NCHUNK) return;
        int b0 = blockIdx.x * NB;
        int ts = ci * CHUNK;

        for (int idx = tid; idx < NB * CHUNK * DI_; idx += 1024) {
            int r = idx / (CHUNK * DI_), off = idx - r * (CHUNK * DI_);
            sS[r][off] = srcs[((long)(b0 + r) * S_ + ts) * DI_ + off];
        }
        float creg = 0.f;
        if (kh < NB) {
            hb[kh][j] = (ci == 0) ? 0.f : H1G[(CHUNK - 1) * 65536 + (b0 + kh) * H_ + j];
            creg = (ci == 0) ? 0.f : C1C[(b0 + kh) * H_ + j];
        }
        float bias0 = b_e1[j], bias1 = b_e1[256 + j], bias2 = b_e1[512 + j], bias3 = b_e1[768 + j];
        float wx[4][DI_];
#pragma unroll
        for (int k = 0; k < DI_; k++) {
            wx[0][k] = wih_e1[j * DI_ + k];
            wx[1][k] = wih_e1[(256 + j) * DI_ + k];
            wx[2][k] = wih_e1[(512 + j) * DI_ + k];
            wx[3][k] = wih_e1[(768 + j) * DI_ + k];
        }

        for (int tt = 0; tt < CHUNK; tt++) {
            __syncthreads();               // hb ready; prev red reads done
            float A[NB][4];
#pragma unroll
            for (int bb = 0; bb < NB; bb++) {
                A[bb][0] = 0.f; A[bb][1] = 0.f; A[bb][2] = 0.f; A[bb][3] = 0.f;
            }
            if (kh == 0) {                 // input projection K=5 (wave-uniform branch)
#pragma unroll
                for (int bb = 0; bb < NB; bb++)
#pragma unroll
                    for (int k = 0; k < DI_; k++) {
                        float xv = sS[bb][tt * DI_ + k];
                        A[bb][0] += xv * wx[0][k];
                        A[bb][1] += xv * wx[1][k];
                        A[bb][2] += xv * wx[2][k];
                        A[bb][3] += xv * wx[3][k];
                    }
            }
#pragma unroll 4
            for (int k4 = k40; k4 < k40 + 16; k4++) {
                float4 w0 = bf4f(whh_e1p[(k4 << 10) + j]);
                float4 w1 = bf4f(whh_e1p[(k4 << 10) + 256 + j]);
                float4 w2 = bf4f(whh_e1p[(k4 << 10) + 512 + j]);
                float4 w3 = bf4f(whh_e1p[(k4 << 10) + 768 + j]);
#pragma unroll
                for (int bb = 0; bb < NB; bb++) {
                    float4 h4 = ((const float4*)&hb[bb][0])[k4];
                    dot4(h4, w0, w1, w2, w3, A[bb][0], A[bb][1], A[bb][2], A[bb][3]);
                }
            }
#pragma unroll
            for (int bb = 0; bb < NB; bb++)
                red[kh][bb][j] = make_float4(A[bb][0], A[bb][1], A[bb][2], A[bb][3]);
            __syncthreads();               // red complete; hb reads done
            if (kh < NB) {
                float a0 = bias0, a1 = bias1, a2 = bias2, a3 = bias3;
#pragma unroll
                for (int kk = 0; kk < 4; kk++) {
                    float4 v = red[kk][kh][j];
                    a0 += v.x; a1 += v.y; a2 += v.z; a3 += v.w;
                }
                float cn, hn;
                lstm_epilogue(a0, a1, a2, a3, creg, cn, hn);
                creg = cn;
                hb[kh][j] = hn;
                H1G[tt * 65536 + (b0 + kh) * H_ + j] = hn;
            }
        }
        if (kh < NB) C1C[(b0 + kh) * H_ + j] = creg;
    } else {
        // ================= layer 2, chunk ci-1 =================
        if (ci < 1) return;
        int b0 = (blockIdx.x - 128) * NB;
        int us = (ci - 1) * CHUNK;

        float creg = 0.f, hlast = 0.f;
        if (kh < NB) {
            hb[kh][j] = (ci == 1) ? 0.f : H2C[(b0 + kh) * H_ + j];
            creg = (ci == 1) ? 0.f : C2C[(b0 + kh) * H_ + j];
        }
        float bias0 = b_e2[j], bias1 = b_e2[256 + j], bias2 = b_e2[512 + j], bias3 = b_e2[768 + j];

        for (int tt = 0; tt < CHUNK; tt++) {
            __syncthreads();               // hb ready; prev red reads done
            float x0 = 0.f, x1 = 0.f, x2 = 0.f, x3 = 0.f;
            if (kh < NB) {                 // prefetch own X2 row (hidden under k4 loop)
                const float* xrow = X2 + ((long)tt * B_ + b0 + kh) * 1024;
                x0 = xrow[j]; x1 = xrow[256 + j]; x2 = xrow[512 + j]; x3 = xrow[768 + j];
            }
            float A[NB][4];
#pragma unroll
            for (int bb = 0; bb < NB; bb++) {
                A[bb][0] = 0.f; A[bb][1] = 0.f; A[bb][2] = 0.f; A[bb][3] = 0.f;
            }
#pragma unroll 4
            for (int k4 = k40; k4 < k40 + 16; k4++) {
                float4 w0 = bf4f(whh_e2p[(k4 << 10) + j]);
                float4 w1 = bf4f(whh_e2p[(k4 << 10) + 256 + j]);
                float4 w2 = bf4f(whh_e2p[(k4 << 10) + 512 + j]);
                float4 w3 = bf4f(whh_e2p[(k4 << 10) + 768 + j]);
#pragma unroll
                for (int bb = 0; bb < NB; bb++) {
                    float4 h4 = ((const float4*)&hb[bb][0])[k4];
                    dot4(h4, w0, w1, w2, w3, A[bb][0], A[bb][1], A[bb][2], A[bb][3]);
                }
            }
#pragma unroll
            for (int bb = 0; bb < NB; bb++)
                red[kh][bb][j] = make_float4(A[bb][0], A[bb][1], A[bb][2], A[bb][3]);
            __syncthreads();               // red complete; hb reads done
            if (kh < NB) {
                float a0 = bias0 + x0, a1 = bias1 + x1, a2 = bias2 + x2, a3 = bias3 + x3;
#pragma unroll
                for (int kk = 0; kk < 4; kk++) {
                    float4 v = red[kk][kh][j];
                    a0 += v.x; a1 += v.y; a2 += v.z; a3 += v.w;
                }
                float cn, hn;
                lstm_epilogue(a0, a1, a2, a3, creg, cn, hn);
                creg = cn;
                hlast = hn;
                hb[kh][j] = hn;
                encbf[(long)(b0 + kh) * ENCSTRIDE + (us + tt) * H_ + j] = __float2bfloat16(hn);
            }
        }
        if (kh < NB) {
            H2C[(b0 + kh) * H_ + j] = hlast;
            C2C[(b0 + kh) * H_ + j] = creg;
        }
    }
}

// ---------------------------------------------------------------------------
// Decoder prologue (r15-proven dec_step v2): cells_0 + E_0.
// 256 blocks x 1024 threads, one batch per block. BF16 cell weights.
// ---------------------------------------------------------------------------
__global__ __launch_bounds__(1024) void dec_step_kernel(
    const float* __restrict__ PRD,
    const float* __restrict__ WEF,       // [1024][5]
    const float* __restrict__ BEF,       // [1024]
    const ushort4* __restrict__ whhd1p,  // packed bf16 [64][1024]
    const ushort4* __restrict__ wihd2p,  // packed bf16 [64][1024]
    const float* __restrict__ b_d2,
    float* __restrict__ H2C,             // in: h2prev, out: h2new (own row only)
    float* __restrict__ C2C,             // in: c2prev, out: c2new (own row only)
    const __hip_bfloat16* __restrict__ enc,
    float* __restrict__ E)               // [S_][B_]
{
    __shared__ float h2s[260];           // h2prev
    __shared__ float h1s[260];
    __shared__ float h2n[260];           // h2 new
    __shared__ float g[1024];            // gate accum staging
    __shared__ float prd[8];
    int tid = threadIdx.x;
    int j = tid;
    int b = blockIdx.x;

    if (tid < 256) h2s[tid] = H2C[b * H_ + tid];
    if (tid < DI_) prd[tid] = PRD[b * DI_ + tid];
    __syncthreads();

    // ---- phase A: cell1 gates ----
    {
        float wef[DI_];
#pragma unroll
        for (int m = 0; m < DI_; m++) wef[m] = WEF[j * DI_ + m];
        float a = BEF[j];
#pragma unroll
        for (int m = 0; m < DI_; m++) a += wef[m] * prd[m];
#pragma unroll 4
        for (int k4 = 0; k4 < 64; k4++) {
            float4 w = bf4f(whhd1p[(k4 << 10) + j]);
            float4 h4 = ((const float4*)&h2s[0])[k4];
            a += h4.x * w.x + h4.y * w.y + h4.z * w.z + h4.w * w.w;
        }
        g[j] = a;
    }
    __syncthreads();
    if (tid < 256) {
        int n = tid;
        float cn, hn;
        lstm_epilogue(g[n], g[256 + n], g[512 + n], g[768 + n],
                      C2C[b * H_ + n], cn, hn);
        h1s[n] = hn;                     // c1 is not carried
    }
    __syncthreads();

    // ---- phase B: cell2 gates (h=c=0, no whh) ----
    {
        float a = b_d2[j];
#pragma unroll 4
        for (int k4 = 0; k4 < 64; k4++) {
            float4 w = bf4f(wihd2p[(k4 << 10) + j]);
            float4 h4 = ((const float4*)&h1s[0])[k4];
            a += h4.x * w.x + h4.y * w.y + h4.z * w.z + h4.w * w.w;
        }
        g[j] = a;
    }
    __syncthreads();
    if (tid < 256) {
        int n = tid;
        float cn, hn;
        lstm_epilogue(g[n], g[256 + n], g[512 + n], g[768 + n], 0.f, cn, hn);
        C2C[b * H_ + n] = cn;
        H2C[b * H_ + n] = hn;
        h2n[n] = hn;
    }
    __syncthreads();

    // ---- phase C: energies (16 waves x 32 s; 4 bf16/lane = 256 = H_) ----
    {
        int wv = tid >> 6, lane = tid & 63;
        const __hip_bfloat16* ep = enc + (long)b * ENCSTRIDE;
        float hreg[4];
#pragma unroll
        for (int q = 0; q < 4; q++) hreg[q] = h2n[(lane << 2) + q];
        for (int si = 0; si < 32; si++) {
            int s = wv + (si << 4);
            union { float2 f2; unsigned short u[4]; } uu;
            uu.f2 = *(const float2*)(ep + s * H_ + (lane << 2));
            float p = hreg[0] * bf2f(uu.u[0]) + hreg[1] * bf2f(uu.u[1]) +
                      hreg[2] * bf2f(uu.u[2]) + hreg[3] * bf2f(uu.u[3]);
#pragma unroll
            for (int off = 32; off > 0; off >>= 1) p += __shfl_down(p, off);
            if (lane == 0) E[s * B_ + b] = p;
        }
    }
}

// ---------------------------------------------------------------------------
// softmax over batch (per s): W[s][b]      grid 512 x 256  (proven; fusing
// this into neighbors regressed 3x -- keep it separate)
// ---------------------------------------------------------------------------
__global__ __launch_bounds__(256) void softmax_kernel(const float* __restrict__ E,
                                                      float* __restrict__ W) {
    __shared__ float red[4];
    int s = blockIdx.x, tid = threadIdx.x;
    float v = E[s * B_ + tid];
    float m = v;
#pragma unroll
    for (int off = 32; off > 0; off >>= 1) m = fmaxf(m, __shfl_down(m, off));
    if ((tid & 63) == 0) red[tid >> 6] = m;
    __syncthreads();
    m = fmaxf(fmaxf(red[0], red[1]), fmaxf(red[2], red[3]));
    __syncthreads();
    float e = expf(v - m);
    float p = e;
#pragma unroll
    for (int off = 32; off > 0; off >>= 1) p += __shfl_down(p, off);
    if ((tid & 63) == 0) red[tid >> 6] = p;
    __syncthreads();
    float sum = red[0] + red[1] + red[2] + red[3];
    W[s * B_ + tid] = e / sum;
}

// ---------------------------------------------------------------------------
// dec_fused: {ctx_t, decout -> pred_t, cells_{t+1}, energies -> E_{t+1}} in
// ONE launch -- all block-local per batch b (pred_t[b] feeds only cell1[b]).
// The fusion seam is ROTATED so both grid-wide deps (E->softmax->W) stay at
// launch boundaries. 256 blocks x 1024 threads (r15-proven shape); ctx phase
// 4-way s-split (4x the parallelism of the old 256-thread ctx_out).
// ---------------------------------------------------------------------------
__global__ __launch_bounds__(1024) void dec_fused_kernel(
    int t,
    const float* __restrict__ W,         // [S_][B_] softmax weights (step t)
    const __hip_bfloat16* __restrict__ enc,
    float* __restrict__ H2C,             // in: h2(t); out: h2(t+1) (own row)
    float* __restrict__ C2C,             // in: c2(t); out: c2(t+1) (own row)
    const float* __restrict__ WEF,       // [1024][5]
    const float* __restrict__ BEF,       // [1024]
    const ushort4* __restrict__ whhd1p,  // packed bf16 [64][1024]
    const ushort4* __restrict__ wihd2p,  // packed bf16 [64][1024]
    const float* __restrict__ b_d2,
    const float* __restrict__ ww, const float* __restrict__ bw,
    const float* __restrict__ wop, const float* __restrict__ bop,
    float* __restrict__ out_ctx,         // OUT1 + t*H_ pre-offset
    float* __restrict__ out0,            // OUT0 + t*DI_ pre-offset
    float* __restrict__ E)               // E_{t+1}
{
    __shared__ float lw[512];            // softmax weights for own b
    __shared__ float h2s[260];           // h2(t)
    __shared__ float pc[4][256];         // ctx partials
    __shared__ float hc[512];            // [h2 | ctx]
    __shared__ float prd[8];             // pred_t
    __shared__ float h1s[260];
    __shared__ float h2n[260];
    __shared__ float g[1024];
    int tid = threadIdx.x;
    int j = tid;
    int b = blockIdx.x;

    if (tid < 512) lw[tid] = W[tid * B_ + b];
    else if (tid < 768) h2s[tid - 512] = H2C[b * H_ + (tid - 512)];
    __syncthreads();

    // ---- ctx: 4-way s-split, thread (sh, jj) sums 128 s-values ----
    {
        int sh = tid >> 8, jj = tid & 255;
        const __hip_bfloat16* ep = enc + (long)b * ENCSTRIDE + jj;
        float acc = 0.f;
        int s0 = sh << 7;
#pragma unroll 8
        for (int s = s0; s < s0 + 128; s++) acc += lw[s] * __bfloat162float(ep[s * H_]);
        pc[sh][jj] = acc;
    }
    __syncthreads();
    if (tid < 256) {
        float cx = pc[0][tid] + pc[1][tid] + pc[2][tid] + pc[3][tid];
        out_ctx[(long)b * (TLEN_ * H_) + tid] = cx;
        hc[tid] = h2s[tid];
        hc[256 + tid] = cx;
    }
    __syncthreads();

    // ---- decout -> pred_t (wave 0) ----
    if (tid < 64) {
        float a[DI_] = {0.f, 0.f, 0.f, 0.f, 0.f};
        for (int k = tid; k < 2 * H_; k += 64) {
            float v = hc[k];
#pragma unroll
            for (int m = 0; m < DI_; m++) a[m] += v * ww[m * (2 * H_) + k];
        }
#pragma unroll
        for (int m = 0; m < DI_; m++)
            for (int off = 32; off > 0; off >>= 1) a[m] += __shfl_down(a[m], off);
        if (tid == 0) {
            float t5[DI_];
#pragma unroll
            for (int m = 0; m < DI_; m++) t5[m] = tanhf(a[m] + bw[m]);
#pragma unroll
            for (int m2 = 0; m2 < DI_; m2++) {
                float o = bop[m2];
#pragma unroll
                for (int m = 0; m < DI_; m++) o += t5[m] * wop[m2 * DI_ + m];
                out0[(long)b * (TLEN_ * DI_) + m2] = o;
                prd[m2] = o;
            }
        }
    }
    if (t == TLEN_ - 1) return;          // uniform branch: last step has no next cells
    __syncthreads();                     // prd visible

    // ---- cell1 gates for step t+1 ----
    {
        float wef[DI_];
#pragma unroll
        for (int m = 0; m < DI_; m++) wef[m] = WEF[j * DI_ + m];
        float a = BEF[j];
#pragma unroll
        for (int m = 0; m < DI_; m++) a += wef[m] * prd[m];
#pragma unroll 4
        for (int k4 = 0; k4 < 64; k4++) {
            float4 w = bf4f(whhd1p[(k4 << 10) + j]);
            float4 h4 = ((const float4*)&h2s[0])[k4];
            a += h4.x * w.x + h4.y * w.y + h4.z * w.z + h4.w * w.w;
        }
        g[j] = a;
    }
    __syncthreads();
    if (tid < 256) {
        int n = tid;
        float cn, hn;
        lstm_epilogue(g[n], g[256 + n], g[512 + n], g[768 + n],
                      C2C[b * H_ + n], cn, hn);
        h1s[n] = hn;                     // c1 is not carried
    }
    __syncthreads();

    // ---- cell2 gates (h=c=0, no whh) ----
    {
        float a = b_d2[j];
#pragma unroll 4
        for (int k4 = 0; k4 < 64; k4++) {
            float4 w = bf4f(wihd2p[(k4 << 10) + j]);
            float4 h4 = ((const float4*)&h1s[0])[k4];
            a += h4.x * w.x + h4.y * w.y + h4.z * w.z + h4.w * w.w;
        }
        g[j] = a;
    }
    __syncthreads();
    if (tid < 256) {
        int n = tid;
        float cn, hn;
        lstm_epilogue(g[n], g[256 + n], g[512 + n], g[768 + n], 0.f, cn, hn);
        C2C[b * H_ + n] = cn;
        H2C[b * H_ + n] = hn;
        h2n[n] = hn;
    }
    __syncthreads();

    // ---- energies -> E_{t+1} (16 waves x 32 s; 4 bf16/lane) ----
    {
        int wv = tid >> 6, lane = tid & 63;
        const __hip_bfloat16* ep = enc + (long)b * ENCSTRIDE;
        float hreg[4];
#pragma unroll
        for (int q = 0; q < 4; q++) hreg[q] = h2n[(lane << 2) + q];
        for (int si = 0; si < 32; si++) {
            int s = wv + (si << 4);
            union { float2 f2; unsigned short u[4]; } uu;
            uu.f2 = *(const float2*)(ep + s * H_ + (lane << 2));
            float p = hreg[0] * bf2f(uu.u[0]) + hreg[1] * bf2f(uu.u[1]) +
                      hreg[2] * bf2f(uu.u[2]) + hreg[3] * bf2f(uu.u[3]);
#pragma unroll
            for (int off = 32; off > 0; off >>= 1) p += __shfl_down(p, off);
            if (lane == 0) E[s * B_ + b] = p;
        }
    }
}

// ---------------------------------------------------------------------------
extern "C" void kernel_launch(void* const* d_in, const int* in_sizes, int n_in,
                              void* d_out, int out_size, void* d_ws, size_t ws_size,
                              hipStream_t stream) {
    const float* srcs   = (const float*)d_in[0];
    const float* wih_e1 = (const float*)d_in[1];
    const float* whh_e1 = (const float*)d_in[2];
    const float* b_e1   = (const float*)d_in[3];
    const float* wih_e2 = (const float*)d_in[4];
    const float* whh_e2 = (const float*)d_in[5];
    const float* b_e2   = (const float*)d_in[6];
    const float* wdi    = (const float*)d_in[7];
    const float* bdi    = (const float*)d_in[8];
    const float* wih_d1 = (const float*)d_in[9];
    const float* whh_d1 = (const float*)d_in[10];
    const float* b_d1   = (const float*)d_in[11];
    const float* wih_d2 = (const float*)d_in[12];
    const float* whh_d2 = (const float*)d_in[13];
    const float* b_d2   = (const float*)d_in[14];
    const float* ww     = (const float*)d_in[15];
    const float* bw     = (const float*)d_in[16];
    const float* wop    = (const float*)d_in[17];
    const float* bop    = (const float*)d_in[18];

    float* ws = (float*)d_ws;
    __hip_bfloat16* ENCBF = (__hip_bfloat16*)d_ws;   // [256][512][256] bf16 = 16,777,216 float slots
    size_t o = 16777216;
    ushort4* PKE1B = (ushort4*)(ws + o); o += 131072; // whh_e1 packed bf16
    ushort4* PKH2B = (ushort4*)(ws + o); o += 131072; // whh_e2 packed bf16
    ushort4* PKD1B = (ushort4*)(ws + o); o += 131072; // whh_d1 packed bf16
    ushort4* PKD2B = (ushort4*)(ws + o); o += 131072; // wih_d2 packed bf16
    ushort4* PKX2B = (ushort4*)(ws + o); o += 131072; // wih_e2 packed bf16
    float* H1G = ws + o; o += 2097152;               // [CHUNK][B][H] e1 chunk (single)
    float* X2G = ws + o; o += 8388608;               // [CHUNK*B][1024] wih_e2 @ e1
    float* C1C = ws + o; o += 65536;                 // layer-1 c carry
    float* H2C = ws + o; o += 65536;                 // layer-2 h carry / decoder h
    float* C2C = ws + o; o += 65536;                 // layer-2 c carry / decoder c
    float* EN  = ws + o; o += 131072;                // energies
    float* WSM = ws + o; o += 131072;                // softmax weights
    float* PRD = ws + o; o += 1280;
    float* WEF = ws + o; o += 5120;
    float* BEF = ws + o; o += 1024;

    float* OUT0 = (float*)d_out;
    float* OUT1 = OUT0 + (size_t)B_ * TLEN_ * DI_;   // context_enc base

    dim3 t256(256);

    init_kernel<<<dim3(8), t256, 0, stream>>>(PRD);

    packbf_kernel<<<dim3(256), t256, 0, stream>>>(whh_e1, PKE1B);
    packbf_kernel<<<dim3(256), t256, 0, stream>>>(whh_e2, PKH2B);
    packbf_kernel<<<dim3(256), t256, 0, stream>>>(whh_d1, PKD1B);
    packbf_kernel<<<dim3(256), t256, 0, stream>>>(wih_d2, PKD2B);
    packbf_kernel<<<dim3(256), t256, 0, stream>>>(wih_e2, PKX2B);
    weff_kernel<<<dim3(4), t256, 0, stream>>>(wih_d1, wdi, bdi, b_d1, WEF, BEF);

    // ---------------- encoder: 17 chunked launches (256 blocks) + 16 xproj ----------------
    for (int ci = 0; ci <= NCHUNK; ci++) {
        enc_chunk_kernel<<<dim3(256), dim3(1024), 0, stream>>>(
            ci, srcs, wih_e1, PKE1B, PKH2B, b_e1, b_e2,
            X2G, H1G, C1C, H2C, C2C, ENCBF);
        if (ci < NCHUNK) {
            xproj_kernel<<<dim3(256), dim3(1024), 0, stream>>>(H1G, PKX2B, X2G);
        }
    }
    // final states: h_enc = H2C, c_enc = C2C

    // ---------------- decoder: prologue + 32 x {softmax, fused} ----------------
    dec_step_kernel<<<dim3(256), dim3(1024), 0, stream>>>(
        PRD, WEF, BEF, PKD1B, PKD2B, b_d2, H2C, C2C, ENCBF, EN);   // cells_0 + E_0
    for (int t = 0; t < TLEN_; t++) {
        softmax_kernel<<<dim3(512), t256, 0, stream>>>(EN, WSM);
        dec_fused_kernel<<<dim3(256), dim3(1024), 0, stream>>>(
            t, WSM, ENCBF, H2C, C2C, WEF, BEF, PKD1B, PKD2B, b_d2,
            ww, bw, wop, bop,
            OUT1 + (size_t)t * H_, OUT0 + (size_t)t * DI_, EN);
    }
}

// Round 19
// 7922.733 us; speedup vs baseline: 1.4624x; 1.0006x over previous
//
#include <hip/hip_runtime.h>
#include <hip/hip_bf16.h>

#define B_    256
#define S_    512
#define H_    256
#define TLEN_ 32
#define DI_   5
#define ENCSTRIDE 131072   // S_*H_
#define CHUNK 32
#define NCHUNK 16          // S_/CHUNK
#define NB 2               // batches per encoder block (256 blocks -> all CUs)

__device__ __forceinline__ float bf2f(unsigned short v) {
    return __uint_as_float(((unsigned)v) << 16);
}
__device__ __forceinline__ unsigned short f2bf(float f) {
    __hip_bfloat16 h = __float2bfloat16(f);
    return *reinterpret_cast<unsigned short*>(&h);
}

// ---------------------------------------------------------------------------
// init: set decoder inp0 = ones
// ---------------------------------------------------------------------------
__global__ __launch_bounds__(256) void init_kernel(float* PRD) {
    int i = blockIdx.x * 256 + threadIdx.x;      // grid 8 -> 2048
    if (i < B_ * DI_) PRD[i] = 1.0f;
}

// ---------------------------------------------------------------------------
// pack bf16 payload (ushort4 = 4 weights / 8B): [1024][256] -> [k4][n].
// ---------------------------------------------------------------------------
__global__ __launch_bounds__(256) void packbf_kernel(const float* __restrict__ m,
                                                     ushort4* __restrict__ out) {
    int idx = blockIdx.x * 256 + threadIdx.x;    // grid 256 -> 65536
    int k4 = idx >> 10, n = idx & 1023;
    float4 v = ((const float4*)m)[n * 64 + k4];
    out[idx] = make_ushort4(f2bf(v.x), f2bf(v.y), f2bf(v.z), f2bf(v.w));
}

// ---------------------------------------------------------------------------
// Weff[n][m] = sum_k wih_d1[n][k]*wdi[k][m]; beff[n] = b_d1[n] + wih_d1[n]·bdi
// ---------------------------------------------------------------------------
__global__ __launch_bounds__(256) void weff_kernel(const float* __restrict__ wih_d1,
                                                   const float* __restrict__ wdi,
                                                   const float* __restrict__ bdi,
                                                   const float* __restrict__ b_d1,
                                                   float* __restrict__ weff,
                                                   float* __restrict__ beff) {
    int n = blockIdx.x * 256 + threadIdx.x;      // grid 4 -> 1024
    float acc[DI_] = {0.f, 0.f, 0.f, 0.f, 0.f};
    float accb = 0.f;
    for (int k = 0; k < H_; k++) {
        float w = wih_d1[n * H_ + k];
        accb += w * bdi[k];
#pragma unroll
        for (int m = 0; m < DI_; m++) acc[m] += w * wdi[k * DI_ + m];
    }
#pragma unroll
    for (int m = 0; m < DI_; m++) weff[n * DI_ + m] = acc[m];
    beff[n] = b_d1[n] + accb;
}

// ---------------------------------------------------------------------------
// dot-chunk helper: a0..a3 += xv · w{0..3}
// ---------------------------------------------------------------------------
__device__ __forceinline__ void dot4(const float4 xv, const float4 w0, const float4 w1,
                                     const float4 w2, const float4 w3,
                                     float& a0, float& a1, float& a2, float& a3) {
    a0 += xv.x * w0.x + xv.y * w0.y + xv.z * w0.z + xv.w * w0.w;
    a1 += xv.x * w1.x + xv.y * w1.y + xv.z * w1.z + xv.w * w1.w;
    a2 += xv.x * w2.x + xv.y * w2.y + xv.z * w2.z + xv.w * w2.w;
    a3 += xv.x * w3.x + xv.y * w3.y + xv.z * w3.z + xv.w * w3.w;
}

__device__ __forceinline__ float4 bf4f(ushort4 u) {
    return make_float4(bf2f(u.x), bf2f(u.y), bf2f(u.z), bf2f(u.w));
}

__device__ __forceinline__ void lstm_epilogue(float a0, float a1, float a2, float a3,
                                              float cold, float& cn, float& hn) {
    float ii = 1.f / (1.f + expf(-a0));
    float ff = 1.f / (1.f + expf(-a1));
    float gg = tanhf(a2);
    float oo = 1.f / (1.f + expf(-a3));
    cn = ff * cold + ii * gg;
    hn = oo * tanhf(cn);
}

// ---------------------------------------------------------------------------
// xproj v3 (barrier-free, r15-proven): X2[row][n] = sum_k wih_e2[n][k]*e1[row][k].
// X2 stays FP32: bf16/fp16 X2 (r17/r18) injects per-step noise into the
// layer-2 recurrence (random-walk amplification over 512 steps) -> absmax
// 1-3e-2 > threshold. Weight bf16 is fine (systematic, gate-contracted);
// activation quantization in the recurrent path is NOT.
// ---------------------------------------------------------------------------
__global__ __launch_bounds__(1024) void xproj_kernel(
    const float* __restrict__ h1,      // [CHUNK][B_][H_] = [8192][256]
    const ushort4* __restrict__ wpb,   // packed bf16 [64][1024] (PKX2B)
    float* __restrict__ X2)            // [8192][1024]
{
    __shared__ float es[32][260];      // 32 staged e1 rows
    int tid = threadIdx.x, j = tid;
    long r0 = (long)blockIdx.x * 32;

    for (int i = tid; i < 2048; i += 1024) {
        int rr = i >> 6, c4 = i & 63;
        ((float4*)&es[rr][0])[c4] = ((const float4*)(h1 + (r0 + rr) * H_))[c4];
    }
    __syncthreads();

    float acc[32];
#pragma unroll
    for (int r = 0; r < 32; r++) acc[r] = 0.f;
    for (int k4 = 0; k4 < 64; k4++) {
        float4 w = bf4f(wpb[(k4 << 10) + j]);
#pragma unroll
        for (int r = 0; r < 32; r++) {
            float4 h4 = ((const float4*)&es[r][0])[k4];
            acc[r] += h4.x * w.x + h4.y * w.y + h4.z * w.z + h4.w * w.w;
        }
    }
#pragma unroll
    for (int r = 0; r < 32; r++) X2[(r0 + r) * 1024 + j] = acc[r];
}

// ---------------------------------------------------------------------------
// Chunked encoder NB=2 with BF16 recurrent weights (r12/r15-proven).
// ---------------------------------------------------------------------------
__global__ __launch_bounds__(1024, 4) void enc_chunk_kernel(
    int ci,
    const float* __restrict__ srcs,
    const float* __restrict__ wih_e1,      // [1024][5] raw
    const ushort4* __restrict__ whh_e1p,   // packed bf16 [64][1024]
    const ushort4* __restrict__ whh_e2p,   // packed bf16 [64][1024]
    const float* __restrict__ b_e1,
    const float* __restrict__ b_e2,
    const float* __restrict__ X2,          // [CHUNK*B_][1024] wih_e2 part (fp32)
    float* __restrict__ H1G,               // [CHUNK][B_][H_] (single buffer)
    float* __restrict__ C1C,               // [B_][H_] layer-1 c carry
    float* __restrict__ H2C,               // [B_][H_] layer-2 h carry (final = h_enc)
    float* __restrict__ C2C,               // [B_][H_] layer-2 c carry (final = c_enc)
    __hip_bfloat16* __restrict__ encbf)    // [b][s][h]
{
    __shared__ float4 red[4][NB][256];     // [kh][bb][j] -> 4 gate partials, 32KB
    __shared__ float hb[NB][260];          // own-layer h (current step)
    __shared__ float sS[NB][160];          // L1 srcs chunk

    int tid = threadIdx.x;
    int kh = tid >> 8;                     // K-slice (accum); bb in reduce (kh<NB)
    int j  = tid & 255;
    int k40 = kh << 4;                     // 16 k4 iterations per slice

    if (blockIdx.x < 128) {
        // ================= layer 1, chunk ci =================
        if (ci >= NCHUNK) return;
        int b0 = blockIdx.x * NB;
        int ts = ci * CHUNK;

        for (int idx = tid; idx < NB * CHUNK * DI_; idx += 1024) {
            int r = idx / (CHUNK * DI_), off = idx - r * (CHUNK * DI_);
            sS[r][off] = srcs[((long)(b0 + r) * S_ + ts) * DI_ + off];
        }
        float creg = 0.f;
        if (kh < NB) {
            hb[kh][j] = (ci == 0) ? 0.f : H1G[(CHUNK - 1) * 65536 + (b0 + kh) * H_ + j];
            creg = (ci == 0) ? 0.f : C1C[(b0 + kh) * H_ + j];
        }
        float bias0 = b_e1[j], bias1 = b_e1[256 + j], bias2 = b_e1[512 + j], bias3 = b_e1[768 + j];
        float wx[4][DI_];
#pragma unroll
        for (int k = 0; k < DI_; k++) {
            wx[0][k] = wih_e1[j * DI_ + k];
            wx[1][k] = wih_e1[(256 + j) * DI_ + k];
            wx[2][k] = wih_e1[(512 + j) * DI_ + k];
            wx[3][k] = wih_e1[(768 + j) * DI_ + k];
        }

        for (int tt = 0; tt < CHUNK; tt++) {
            __syncthreads();               // hb ready; prev red reads done
            float A[NB][4];
#pragma unroll
            for (int bb = 0; bb < NB; bb++) {
                A[bb][0] = 0.f; A[bb][1] = 0.f; A[bb][2] = 0.f; A[bb][3] = 0.f;
            }
            if (kh == 0) {                 // input projection K=5 (wave-uniform branch)
#pragma unroll
                for (int bb = 0; bb < NB; bb++)
#pragma unroll
                    for (int k = 0; k < DI_; k++) {
                        float xv = sS[bb][tt * DI_ + k];
                        A[bb][0] += xv * wx[0][k];
                        A[bb][1] += xv * wx[1][k];
                        A[bb][2] += xv * wx[2][k];
                        A[bb][3] += xv * wx[3][k];
                    }
            }
#pragma unroll 4
            for (int k4 = k40; k4 < k40 + 16; k4++) {
                float4 w0 = bf4f(whh_e1p[(k4 << 10) + j]);
                float4 w1 = bf4f(whh_e1p[(k4 << 10) + 256 + j]);
                float4 w2 = bf4f(whh_e1p[(k4 << 10) + 512 + j]);
                float4 w3 = bf4f(whh_e1p[(k4 << 10) + 768 + j]);
#pragma unroll
                for (int bb = 0; bb < NB; bb++) {
                    float4 h4 = ((const float4*)&hb[bb][0])[k4];
                    dot4(h4, w0, w1, w2, w3, A[bb][0], A[bb][1], A[bb][2], A[bb][3]);
                }
            }
#pragma unroll
            for (int bb = 0; bb < NB; bb++)
                red[kh][bb][j] = make_float4(A[bb][0], A[bb][1], A[bb][2], A[bb][3]);
            __syncthreads();               // red complete; hb reads done
            if (kh < NB) {
                float a0 = bias0, a1 = bias1, a2 = bias2, a3 = bias3;
#pragma unroll
                for (int kk = 0; kk < 4; kk++) {
                    float4 v = red[kk][kh][j];
                    a0 += v.x; a1 += v.y; a2 += v.z; a3 += v.w;
                }
                float cn, hn;
                lstm_epilogue(a0, a1, a2, a3, creg, cn, hn);
                creg = cn;
                hb[kh][j] = hn;
                H1G[tt * 65536 + (b0 + kh) * H_ + j] = hn;
            }
        }
        if (kh < NB) C1C[(b0 + kh) * H_ + j] = creg;
    } else {
        // ================= layer 2, chunk ci-1 =================
        if (ci < 1) return;
        int b0 = (blockIdx.x - 128) * NB;
        int us = (ci - 1) * CHUNK;

        float creg = 0.f, hlast = 0.f;
        if (kh < NB) {
            hb[kh][j] = (ci == 1) ? 0.f : H2C[(b0 + kh) * H_ + j];
            creg = (ci == 1) ? 0.f : C2C[(b0 + kh) * H_ + j];
        }
        float bias0 = b_e2[j], bias1 = b_e2[256 + j], bias2 = b_e2[512 + j], bias3 = b_e2[768 + j];

        for (int tt = 0; tt < CHUNK; tt++) {
            __syncthreads();               // hb ready; prev red reads done
            float x0 = 0.f, x1 = 0.f, x2 = 0.f, x3 = 0.f;
            if (kh < NB) {                 // prefetch own X2 row (hidden under k4 loop)
                const float* xrow = X2 + ((long)tt * B_ + b0 + kh) * 1024;
                x0 = xrow[j]; x1 = xrow[256 + j]; x2 = xrow[512 + j]; x3 = xrow[768 + j];
            }
            float A[NB][4];
#pragma unroll
            for (int bb = 0; bb < NB; bb++) {
                A[bb][0] = 0.f; A[bb][1] = 0.f; A[bb][2] = 0.f; A[bb][3] = 0.f;
            }
#pragma unroll 4
            for (int k4 = k40; k4 < k40 + 16; k4++) {
                float4 w0 = bf4f(whh_e2p[(k4 << 10) + j]);
                float4 w1 = bf4f(whh_e2p[(k4 << 10) + 256 + j]);
                float4 w2 = bf4f(whh_e2p[(k4 << 10) + 512 + j]);
                float4 w3 = bf4f(whh_e2p[(k4 << 10) + 768 + j]);
#pragma unroll
                for (int bb = 0; bb < NB; bb++) {
                    float4 h4 = ((const float4*)&hb[bb][0])[k4];
                    dot4(h4, w0, w1, w2, w3, A[bb][0], A[bb][1], A[bb][2], A[bb][3]);
                }
            }
#pragma unroll
            for (int bb = 0; bb < NB; bb++)
                red[kh][bb][j] = make_float4(A[bb][0], A[bb][1], A[bb][2], A[bb][3]);
            __syncthreads();               // red complete; hb reads done
            if (kh < NB) {
                float a0 = bias0 + x0, a1 = bias1 + x1, a2 = bias2 + x2, a3 = bias3 + x3;
#pragma unroll
                for (int kk = 0; kk < 4; kk++) {
                    float4 v = red[kk][kh][j];
                    a0 += v.x; a1 += v.y; a2 += v.z; a3 += v.w;
                }
                float cn, hn;
                lstm_epilogue(a0, a1, a2, a3, creg, cn, hn);
                creg = cn;
                hlast = hn;
                hb[kh][j] = hn;
                encbf[(long)(b0 + kh) * ENCSTRIDE + (us + tt) * H_ + j] = __float2bfloat16(hn);
            }
        }
        if (kh < NB) {
            H2C[(b0 + kh) * H_ + j] = hlast;
            C2C[(b0 + kh) * H_ + j] = creg;
        }
    }
}

// ---------------------------------------------------------------------------
// Decoder prologue (r15-proven): cells_0 + E_0.
// 256 blocks x 1024 threads, one batch per block. BF16 cell weights.
// ---------------------------------------------------------------------------
__global__ __launch_bounds__(1024) void dec_step_kernel(
    const float* __restrict__ PRD,
    const float* __restrict__ WEF,       // [1024][5]
    const float* __restrict__ BEF,       // [1024]
    const ushort4* __restrict__ whhd1p,  // packed bf16 [64][1024]
    const ushort4* __restrict__ wihd2p,  // packed bf16 [64][1024]
    const float* __restrict__ b_d2,
    float* __restrict__ H2C,             // in: h2prev, out: h2new (own row only)
    float* __restrict__ C2C,             // in: c2prev, out: c2new (own row only)
    const __hip_bfloat16* __restrict__ enc,
    float* __restrict__ E)               // [S_][B_]
{
    __shared__ float h2s[260];           // h2prev
    __shared__ float h1s[260];
    __shared__ float h2n[260];           // h2 new
    __shared__ float g[1024];            // gate accum staging
    __shared__ float prd[8];
    int tid = threadIdx.x;
    int j = tid;
    int b = blockIdx.x;

    if (tid < 256) h2s[tid] = H2C[b * H_ + tid];
    if (tid < DI_) prd[tid] = PRD[b * DI_ + tid];
    __syncthreads();

    // ---- phase A: cell1 gates ----
    {
        float wef[DI_];
#pragma unroll
        for (int m = 0; m < DI_; m++) wef[m] = WEF[j * DI_ + m];
        float a = BEF[j];
#pragma unroll
        for (int m = 0; m < DI_; m++) a += wef[m] * prd[m];
#pragma unroll 4
        for (int k4 = 0; k4 < 64; k4++) {
            float4 w = bf4f(whhd1p[(k4 << 10) + j]);
            float4 h4 = ((const float4*)&h2s[0])[k4];
            a += h4.x * w.x + h4.y * w.y + h4.z * w.z + h4.w * w.w;
        }
        g[j] = a;
    }
    __syncthreads();
    if (tid < 256) {
        int n = tid;
        float cn, hn;
        lstm_epilogue(g[n], g[256 + n], g[512 + n], g[768 + n],
                      C2C[b * H_ + n], cn, hn);
        h1s[n] = hn;                     // c1 is not carried
    }
    __syncthreads();

    // ---- phase B: cell2 gates (h=c=0, no whh) ----
    {
        float a = b_d2[j];
#pragma unroll 4
        for (int k4 = 0; k4 < 64; k4++) {
            float4 w = bf4f(wihd2p[(k4 << 10) + j]);
            float4 h4 = ((const float4*)&h1s[0])[k4];
            a += h4.x * w.x + h4.y * w.y + h4.z * w.z + h4.w * w.w;
        }
        g[j] = a;
    }
    __syncthreads();
    if (tid < 256) {
        int n = tid;
        float cn, hn;
        lstm_epilogue(g[n], g[256 + n], g[512 + n], g[768 + n], 0.f, cn, hn);
        C2C[b * H_ + n] = cn;
        H2C[b * H_ + n] = hn;
        h2n[n] = hn;
    }
    __syncthreads();

    // ---- phase C: energies (16 waves x 32 s; 4 bf16/lane = 256 = H_) ----
    {
        int wv = tid >> 6, lane = tid & 63;
        const __hip_bfloat16* ep = enc + (long)b * ENCSTRIDE;
        float hreg[4];
#pragma unroll
        for (int q = 0; q < 4; q++) hreg[q] = h2n[(lane << 2) + q];
        for (int si = 0; si < 32; si++) {
            int s = wv + (si << 4);
            union { float2 f2; unsigned short u[4]; } uu;
            uu.f2 = *(const float2*)(ep + s * H_ + (lane << 2));
            float p = hreg[0] * bf2f(uu.u[0]) + hreg[1] * bf2f(uu.u[1]) +
                      hreg[2] * bf2f(uu.u[2]) + hreg[3] * bf2f(uu.u[3]);
#pragma unroll
            for (int off = 32; off > 0; off >>= 1) p += __shfl_down(p, off);
            if (lane == 0) E[s * B_ + b] = p;
        }
    }
}

// ---------------------------------------------------------------------------
// softmax over batch (per s): W[s][b]      grid 512 x 256  (proven; fusing
// this into neighbors regressed 3x -- keep it separate)
// ---------------------------------------------------------------------------
__global__ __launch_bounds__(256) void softmax_kernel(const float* __restrict__ E,
                                                      float* __restrict__ W) {
    __shared__ float red[4];
    int s = blockIdx.x, tid = threadIdx.x;
    float v = E[s * B_ + tid];
    float m = v;
#pragma unroll
    for (int off = 32; off > 0; off >>= 1) m = fmaxf(m, __shfl_down(m, off));
    if ((tid & 63) == 0) red[tid >> 6] = m;
    __syncthreads();
    m = fmaxf(fmaxf(red[0], red[1]), fmaxf(red[2], red[3]));
    __syncthreads();
    float e = expf(v - m);
    float p = e;
#pragma unroll
    for (int off = 32; off > 0; off >>= 1) p += __shfl_down(p, off);
    if ((tid & 63) == 0) red[tid >> 6] = p;
    __syncthreads();
    float sum = red[0] + red[1] + red[2] + red[3];
    W[s * B_ + tid] = e / sum;
}

// ---------------------------------------------------------------------------
// dec_fused (r16-proven): {ctx_t, decout -> pred_t, cells_{t+1}, energies ->
// E_{t+1}} in ONE launch -- all block-local per batch b. Fusion seam rotated
// so both grid-wide deps (E->softmax->W) stay at launch boundaries.
// ---------------------------------------------------------------------------
__global__ __launch_bounds__(1024) void dec_fused_kernel(
    int t,
    const float* __restrict__ W,         // [S_][B_] softmax weights (step t)
    const __hip_bfloat16* __restrict__ enc,
    float* __restrict__ H2C,             // in: h2(t); out: h2(t+1) (own row)
    float* __restrict__ C2C,             // in: c2(t); out: c2(t+1) (own row)
    const float* __restrict__ WEF,       // [1024][5]
    const float* __restrict__ BEF,       // [1024]
    const ushort4* __restrict__ whhd1p,  // packed bf16 [64][1024]
    const ushort4* __restrict__ wihd2p,  // packed bf16 [64][1024]
    const float* __restrict__ b_d2,
    const float* __restrict__ ww, const float* __restrict__ bw,
    const float* __restrict__ wop, const float* __restrict__ bop,
    float* __restrict__ out_ctx,         // OUT1 + t*H_ pre-offset
    float* __restrict__ out0,            // OUT0 + t*DI_ pre-offset
    float* __restrict__ E)               // E_{t+1}
{
    __shared__ float lw[512];            // softmax weights for own b
    __shared__ float h2s[260];           // h2(t)
    __shared__ float pc[4][256];         // ctx partials
    __shared__ float hc[512];            // [h2 | ctx]
    __shared__ float prd[8];             // pred_t
    __shared__ float h1s[260];
    __shared__ float h2n[260];
    __shared__ float g[1024];
    int tid = threadIdx.x;
    int j = tid;
    int b = blockIdx.x;

    if (tid < 512) lw[tid] = W[tid * B_ + b];
    else if (tid < 768) h2s[tid - 512] = H2C[b * H_ + (tid - 512)];
    __syncthreads();

    // ---- ctx: 4-way s-split, thread (sh, jj) sums 128 s-values ----
    {
        int sh = tid >> 8, jj = tid & 255;
        const __hip_bfloat16* ep = enc + (long)b * ENCSTRIDE + jj;
        float acc = 0.f;
        int s0 = sh << 7;
#pragma unroll 8
        for (int s = s0; s < s0 + 128; s++) acc += lw[s] * __bfloat162float(ep[s * H_]);
        pc[sh][jj] = acc;
    }
    __syncthreads();
    if (tid < 256) {
        float cx = pc[0][tid] + pc[1][tid] + pc[2][tid] + pc[3][tid];
        out_ctx[(long)b * (TLEN_ * H_) + tid] = cx;
        hc[tid] = h2s[tid];
        hc[256 + tid] = cx;
    }
    __syncthreads();

    // ---- decout -> pred_t (wave 0) ----
    if (tid < 64) {
        float a[DI_] = {0.f, 0.f, 0.f, 0.f, 0.f};
        for (int k = tid; k < 2 * H_; k += 64) {
            float v = hc[k];
#pragma unroll
            for (int m = 0; m < DI_; m++) a[m] += v * ww[m * (2 * H_) + k];
        }
#pragma unroll
        for (int m = 0; m < DI_; m++)
            for (int off = 32; off > 0; off >>= 1) a[m] += __shfl_down(a[m], off);
        if (tid == 0) {
            float t5[DI_];
#pragma unroll
            for (int m = 0; m < DI_; m++) t5[m] = tanhf(a[m] + bw[m]);
#pragma unroll
            for (int m2 = 0; m2 < DI_; m2++) {
                float o = bop[m2];
#pragma unroll
                for (int m = 0; m < DI_; m++) o += t5[m] * wop[m2 * DI_ + m];
                out0[(long)b * (TLEN_ * DI_) + m2] = o;
                prd[m2] = o;
            }
        }
    }
    if (t == TLEN_ - 1) return;          // uniform branch: last step has no next cells
    __syncthreads();                     // prd visible

    // ---- cell1 gates for step t+1 ----
    {
        float wef[DI_];
#pragma unroll
        for (int m = 0; m < DI_; m++) wef[m] = WEF[j * DI_ + m];
        float a = BEF[j];
#pragma unroll
        for (int m = 0; m < DI_; m++) a += wef[m] * prd[m];
#pragma unroll 4
        for (int k4 = 0; k4 < 64; k4++) {
            float4 w = bf4f(whhd1p[(k4 << 10) + j]);
            float4 h4 = ((const float4*)&h2s[0])[k4];
            a += h4.x * w.x + h4.y * w.y + h4.z * w.z + h4.w * w.w;
        }
        g[j] = a;
    }
    __syncthreads();
    if (tid < 256) {
        int n = tid;
        float cn, hn;
        lstm_epilogue(g[n], g[256 + n], g[512 + n], g[768 + n],
                      C2C[b * H_ + n], cn, hn);
        h1s[n] = hn;                     // c1 is not carried
    }
    __syncthreads();

    // ---- cell2 gates (h=c=0, no whh) ----
    {
        float a = b_d2[j];
#pragma unroll 4
        for (int k4 = 0; k4 < 64; k4++) {
            float4 w = bf4f(wihd2p[(k4 << 10) + j]);
            float4 h4 = ((const float4*)&h1s[0])[k4];
            a += h4.x * w.x + h4.y * w.y + h4.z * w.z + h4.w * w.w;
        }
        g[j] = a;
    }
    __syncthreads();
    if (tid < 256) {
        int n = tid;
        float cn, hn;
        lstm_epilogue(g[n], g[256 + n], g[512 + n], g[768 + n], 0.f, cn, hn);
        C2C[b * H_ + n] = cn;
        H2C[b * H_ + n] = hn;
        h2n[n] = hn;
    }
    __syncthreads();

    // ---- energies -> E_{t+1} (16 waves x 32 s; 4 bf16/lane) ----
    {
        int wv = tid >> 6, lane = tid & 63;
        const __hip_bfloat16* ep = enc + (long)b * ENCSTRIDE;
        float hreg[4];
#pragma unroll
        for (int q = 0; q < 4; q++) hreg[q] = h2n[(lane << 2) + q];
        for (int si = 0; si < 32; si++) {
            int s = wv + (si << 4);
            union { float2 f2; unsigned short u[4]; } uu;
            uu.f2 = *(const float2*)(ep + s * H_ + (lane << 2));
            float p = hreg[0] * bf2f(uu.u[0]) + hreg[1] * bf2f(uu.u[1]) +
                      hreg[2] * bf2f(uu.u[2]) + hreg[3] * bf2f(uu.u[3]);
#pragma unroll
            for (int off = 32; off > 0; off >>= 1) p += __shfl_down(p, off);
            if (lane == 0) E[s * B_ + b] = p;
        }
    }
}

// ---------------------------------------------------------------------------
extern "C" void kernel_launch(void* const* d_in, const int* in_sizes, int n_in,
                              void* d_out, int out_size, void* d_ws, size_t ws_size,
                              hipStream_t stream) {
    const float* srcs   = (const float*)d_in[0];
    const float* wih_e1 = (const float*)d_in[1];
    const float* whh_e1 = (const float*)d_in[2];
    const float* b_e1   = (const float*)d_in[3];
    const float* wih_e2 = (const float*)d_in[4];
    const float* whh_e2 = (const float*)d_in[5];
    const float* b_e2   = (const float*)d_in[6];
    const float* wdi    = (const float*)d_in[7];
    const float* bdi    = (const float*)d_in[8];
    const float* wih_d1 = (const float*)d_in[9];
    const float* whh_d1 = (const float*)d_in[10];
    const float* b_d1   = (const float*)d_in[11];
    const float* wih_d2 = (const float*)d_in[12];
    const float* whh_d2 = (const float*)d_in[13];
    const float* b_d2   = (const float*)d_in[14];
    const float* ww     = (const float*)d_in[15];
    const float* bw     = (const float*)d_in[16];
    const float* wop    = (const float*)d_in[17];
    const float* bop    = (const float*)d_in[18];

    float* ws = (float*)d_ws;
    __hip_bfloat16* ENCBF = (__hip_bfloat16*)d_ws;   // [256][512][256] bf16 = 16,777,216 float slots
    size_t o = 16777216;
    ushort4* PKE1B = (ushort4*)(ws + o); o += 131072; // whh_e1 packed bf16
    ushort4* PKH2B = (ushort4*)(ws + o); o += 131072; // whh_e2 packed bf16
    ushort4* PKD1B = (ushort4*)(ws + o); o += 131072; // whh_d1 packed bf16
    ushort4* PKD2B = (ushort4*)(ws + o); o += 131072; // wih_d2 packed bf16
    ushort4* PKX2B = (ushort4*)(ws + o); o += 131072; // wih_e2 packed bf16
    float* H1G = ws + o; o += 2097152;               // [CHUNK][B][H] e1 chunk (single)
    float* X2G = ws + o; o += 8388608;               // [CHUNK*B][1024] wih_e2 @ e1 (fp32)
    float* C1C = ws + o; o += 65536;                 // layer-1 c carry
    float* H2C = ws + o; o += 65536;                 // layer-2 h carry / decoder h
    float* C2C = ws + o; o += 65536;                 // layer-2 c carry / decoder c
    float* EN  = ws + o; o += 131072;                // energies
    float* WSM = ws + o; o += 131072;                // softmax weights
    float* PRD = ws + o; o += 1280;
    float* WEF = ws + o; o += 5120;
    float* BEF = ws + o; o += 1024;

    float* OUT0 = (float*)d_out;
    float* OUT1 = OUT0 + (size_t)B_ * TLEN_ * DI_;   // context_enc base

    dim3 t256(256);

    init_kernel<<<dim3(8), t256, 0, stream>>>(PRD);

    packbf_kernel<<<dim3(256), t256, 0, stream>>>(whh_e1, PKE1B);
    packbf_kernel<<<dim3(256), t256, 0, stream>>>(whh_e2, PKH2B);
    packbf_kernel<<<dim3(256), t256, 0, stream>>>(whh_d1, PKD1B);
    packbf_kernel<<<dim3(256), t256, 0, stream>>>(wih_d2, PKD2B);
    packbf_kernel<<<dim3(256), t256, 0, stream>>>(wih_e2, PKX2B);
    weff_kernel<<<dim3(4), t256, 0, stream>>>(wih_d1, wdi, bdi, b_d1, WEF, BEF);

    // ---------------- encoder: 17 chunked launches (256 blocks) + 16 xproj ----------------
    for (int ci = 0; ci <= NCHUNK; ci++) {
        enc_chunk_kernel<<<dim3(256), dim3(1024), 0, stream>>>(
            ci, srcs, wih_e1, PKE1B, PKH2B, b_e1, b_e2,
            X2G, H1G, C1C, H2C, C2C, ENCBF);
        if (ci < NCHUNK) {
            xproj_kernel<<<dim3(256), dim3(1024), 0, stream>>>(H1G, PKX2B, X2G);
        }
    }
    // final states: h_enc = H2C, c_enc = C2C

    // ---------------- decoder: prologue + 32 x {softmax, fused} ----------------
    dec_step_kernel<<<dim3(256), dim3(1024), 0, stream>>>(
        PRD, WEF, BEF, PKD1B, PKD2B, b_d2, H2C, C2C, ENCBF, EN);   // cells_0 + E_0
    for (int t = 0; t < TLEN_; t++) {
        softmax_kernel<<<dim3(512), t256, 0, stream>>>(EN, WSM);
        dec_fused_kernel<<<dim3(256), dim3(1024), 0, stream>>>(
            t, WSM, ENCBF, H2C, C2C, WEF, BEF, PKD1B, PKD2B, b_d2,
            ww, bw, wop, bop,
            OUT1 + (size_t)t * H_, OUT0 + (size_t)t * DI_, EN);
    }
}